// Round 1
// baseline (1188.115 us; speedup 1.0000x reference)
//
#include <hip/hip_runtime.h>
#include <math.h>

typedef unsigned short u16;
typedef __attribute__((ext_vector_type(8))) short short8;
typedef __attribute__((ext_vector_type(8))) u16 u16x8;
typedef __attribute__((ext_vector_type(4))) float f32x4;

#define NTOK 16384   // B*S
#define DDIM 512
#define FDIM 2048
#define ENUM 8
#define APAD (32768 + 256)   // assignments (=2*NTOK) + tile padding

__device__ __forceinline__ u16 f2bf(float f) {
  unsigned u = __float_as_uint(f);
  u += 0x7FFFu + ((u >> 16) & 1u);   // RNE
  return (u16)(u >> 16);
}

// ---------------- router: logits, softmax, top2, gate partial sums ----------
__global__ __launch_bounds__(256) void router_kernel(
    const float* __restrict__ x, const float* __restrict__ Wr,
    const float* __restrict__ br, int* __restrict__ top2e,
    float* __restrict__ top2v, int* __restrict__ counts,
    float* __restrict__ gatePart) {
  __shared__ float sWr[DDIM * ENUM];
  __shared__ float sGate[ENUM];
  int tid = threadIdx.x;
  for (int i = tid; i < DDIM * ENUM; i += 256) sWr[i] = Wr[i];
  if (tid < ENUM) sGate[tid] = 0.f;
  __syncthreads();
  int wave = tid >> 6, lane = tid & 63;
  int t = blockIdx.x * 4 + wave;
  int e = lane & 7, dg = lane >> 3;  // lane -> (expert, d-group of 64)
  const float4* xr = (const float4*)(x + (size_t)t * DDIM);
  float acc = 0.f;
#pragma unroll
  for (int i = 0; i < 16; ++i) {
    float4 v = xr[dg * 16 + i];
    int d = dg * 64 + i * 4;
    acc += v.x * sWr[(d + 0) * 8 + e];
    acc += v.y * sWr[(d + 1) * 8 + e];
    acc += v.z * sWr[(d + 2) * 8 + e];
    acc += v.w * sWr[(d + 3) * 8 + e];
  }
  // reduce across d-groups (lanes stride 8)
  acc += __shfl_xor(acc, 8);
  acc += __shfl_xor(acc, 16);
  acc += __shfl_xor(acc, 32);
  float logit = acc + br[e];
  // softmax across the 8-lane expert group
  float m = logit;
  m = fmaxf(m, __shfl_xor(m, 1));
  m = fmaxf(m, __shfl_xor(m, 2));
  m = fmaxf(m, __shfl_xor(m, 4));
  float pv = expf(logit - m);
  float s = pv;
  s += __shfl_xor(s, 1);
  s += __shfl_xor(s, 2);
  s += __shfl_xor(s, 4);
  float gate = pv / s;
  // top1 (ties -> lowest index, matching lax.top_k)
  float v1 = gate; int i1 = e;
#pragma unroll
  for (int msk = 1; msk <= 4; msk <<= 1) {
    float ov = __shfl_xor(v1, msk);
    int oi = __shfl_xor(i1, msk);
    if (ov > v1 || (ov == v1 && oi < i1)) { v1 = ov; i1 = oi; }
  }
  float g2 = (e == i1) ? -1.f : gate;
  float v2 = g2; int i2 = e;
#pragma unroll
  for (int msk = 1; msk <= 4; msk <<= 1) {
    float ov = __shfl_xor(v2, msk);
    int oi = __shfl_xor(i2, msk);
    if (ov > v2 || (ov == v2 && oi < i2)) { v2 = ov; i2 = oi; }
  }
  if (lane == 0) {
    top2e[2 * t] = i1; top2e[2 * t + 1] = i2;
    top2v[2 * t] = v1; top2v[2 * t + 1] = v2;
    atomicAdd(&counts[i1], 1);
    atomicAdd(&counts[i2], 1);
  }
  if (lane < 8) atomicAdd(&sGate[e], gate);
  __syncthreads();
  if (tid < 8) gatePart[blockIdx.x * 8 + tid] = sGate[tid];
}

// ---------------- finalize: offsets/cursors + aux loss ----------------------
__global__ __launch_bounds__(256) void finalize_kernel(
    const int* __restrict__ counts, int* __restrict__ offsets,
    int* __restrict__ cursor, const float* __restrict__ gatePart,
    float* __restrict__ auxOut) {
  __shared__ float sG[ENUM];
  int tid = threadIdx.x;
  if (tid < ENUM) sG[tid] = 0.f;
  __syncthreads();
  float loc[8] = {0, 0, 0, 0, 0, 0, 0, 0};
  for (int r = tid; r < 4096; r += 256) {
#pragma unroll
    for (int e = 0; e < 8; ++e) loc[e] += gatePart[r * 8 + e];
  }
#pragma unroll
  for (int e = 0; e < 8; ++e) atomicAdd(&sG[e], loc[e]);
  __syncthreads();
  if (tid == 0) {
    int off = 0;
#pragma unroll
    for (int e = 0; e < 8; ++e) { offsets[e] = off; cursor[e] = off; off += counts[e]; }
    float aux = 0.f;
#pragma unroll
    for (int e = 0; e < 8; ++e) {
      float pr = sG[e] / (float)NTOK;
      aux += pr * logf(pr + 1e-9f);
    }
    *auxOut = aux;
  }
}

// ---------------- place: assignment lists + gathered bf16 X -----------------
__global__ __launch_bounds__(256) void place_kernel(
    const float* __restrict__ x, const int* __restrict__ top2e,
    const float* __restrict__ top2v, int* __restrict__ cursor,
    int* __restrict__ assignTok, float* __restrict__ assignW,
    u16* __restrict__ Xg) {
  int wave = threadIdx.x >> 6, lane = threadIdx.x & 63;
  int t = blockIdx.x * 4 + wave;
  int a1 = 0, a2 = 0;
  if (lane == 0) {
    int e1 = top2e[2 * t], e2 = top2e[2 * t + 1];
    a1 = atomicAdd(&cursor[e1], 1);
    a2 = atomicAdd(&cursor[e2], 1);
    assignTok[a1] = t; assignW[a1] = top2v[2 * t];
    assignTok[a2] = t; assignW[a2] = top2v[2 * t + 1];
  }
  a1 = __shfl(a1, 0);
  a2 = __shfl(a2, 0);
  const float4* xr = (const float4*)(x + (size_t)t * DDIM);
  float4 v0 = xr[lane * 2], v1 = xr[lane * 2 + 1];
  u16x8 o;
  o[0] = f2bf(v0.x); o[1] = f2bf(v0.y); o[2] = f2bf(v0.z); o[3] = f2bf(v0.w);
  o[4] = f2bf(v1.x); o[5] = f2bf(v1.y); o[6] = f2bf(v1.z); o[7] = f2bf(v1.w);
  *(u16x8*)(Xg + (size_t)a1 * DDIM + lane * 8) = o;
  *(u16x8*)(Xg + (size_t)a2 * DDIM + lane * 8) = o;
}

// ---------------- weight transpose+convert: [K][N] f32 -> [N][K] bf16 -------
__global__ __launch_bounds__(256) void transpose_kernel(
    const float* __restrict__ W, u16* __restrict__ WT, int K, int N) {
  __shared__ float tile[64][65];
  int e = blockIdx.y;
  int tn_count = N >> 6;
  int tk = blockIdx.x / tn_count;
  int tn = blockIdx.x - tk * tn_count;
  const float* Wp = W + (size_t)e * K * N;
  u16* WTp = WT + (size_t)e * N * K;
  int c = threadIdx.x & 63, r = threadIdx.x >> 6;
#pragma unroll
  for (int i = 0; i < 16; ++i) {
    int row = r + i * 4;
    tile[row][c] = Wp[(size_t)(tk * 64 + row) * N + tn * 64 + c];
  }
  __syncthreads();
#pragma unroll
  for (int i = 0; i < 16; ++i) {
    int row = r + i * 4;  // n index within tile
    WTp[(size_t)(tn * 64 + row) * K + tk * 64 + c] = f2bf(tile[c][row]);
  }
}

// ---------------- shared GEMM mainloop: 128x128 tile, BK=32, 4 waves --------
// A: [rows][K] bf16 row-major; B: [ncols][K] bf16 (N-major); both frag-friendly.
template <int K>
__device__ __forceinline__ void gemm_mainloop(const u16* A, const u16* B,
                                              u16* As, u16* Bs,
                                              f32x4 (&acc)[4][4]) {
  int tid = threadIdx.x;
  int wave = tid >> 6, lane = tid & 63;
  int wr = wave >> 1, wc = wave & 1;
  int c0 = tid, c1 = tid + 256;          // 16B chunk ids, 512 per tile
  int r0c = c0 >> 2, k0c = (c0 & 3) * 8; // chunk -> (row, k-offset)
  int r1c = c1 >> 2, k1c = (c1 & 3) * 8;
  int fr = lane & 15, fk = (lane >> 4) * 8;
  for (int k0 = 0; k0 < K; k0 += 32) {
    short8 va0 = *(const short8*)(A + (size_t)r0c * K + k0 + k0c);
    short8 va1 = *(const short8*)(A + (size_t)r1c * K + k0 + k1c);
    short8 vb0 = *(const short8*)(B + (size_t)r0c * K + k0 + k0c);
    short8 vb1 = *(const short8*)(B + (size_t)r1c * K + k0 + k1c);
    __syncthreads();
    *(short8*)(As + c0 * 8) = va0;
    *(short8*)(As + c1 * 8) = va1;
    *(short8*)(Bs + c0 * 8) = vb0;
    *(short8*)(Bs + c1 * 8) = vb1;
    __syncthreads();
    short8 af[4], bf[4];
#pragma unroll
    for (int m = 0; m < 4; ++m)
      af[m] = *(const short8*)(As + (wr * 64 + m * 16 + fr) * 32 + fk);
#pragma unroll
    for (int n = 0; n < 4; ++n)
      bf[n] = *(const short8*)(Bs + (wc * 64 + n * 16 + fr) * 32 + fk);
#pragma unroll
    for (int m = 0; m < 4; ++m)
#pragma unroll
      for (int n = 0; n < 4; ++n)
        acc[m][n] = __builtin_amdgcn_mfma_f32_16x16x32_bf16(af[m], bf[n],
                                                            acc[m][n], 0, 0, 0);
  }
}

// ---------------- GEMM1: h = relu(Xg @ W1 + b1), bf16 out -------------------
__global__ __launch_bounds__(256) void gemm1_kernel(
    const u16* __restrict__ Xg, const u16* __restrict__ W1T,
    const float* __restrict__ b1, u16* __restrict__ h,
    const int* __restrict__ counts, const int* __restrict__ offsets) {
  int e = blockIdx.y;
  int cnt = counts[e];
  int mtile = blockIdx.x & 127, ntile = blockIdx.x >> 7;
  if (mtile * 128 >= cnt) return;
  int off = offsets[e];
  const u16* A = Xg + (size_t)(off + mtile * 128) * DDIM;
  const u16* B = W1T + ((size_t)e * FDIM + ntile * 128) * DDIM;
  __shared__ u16 As[128 * 32];
  __shared__ u16 Bs[128 * 32];
  f32x4 acc[4][4] = {};
  gemm_mainloop<DDIM>(A, B, As, Bs, acc);
  int lane = threadIdx.x & 63, wave = threadIdx.x >> 6;
  int wr = wave >> 1, wc = wave & 1;
  int cl = lane & 15, rq = (lane >> 4) * 4;
#pragma unroll
  for (int m = 0; m < 4; ++m) {
#pragma unroll
    for (int i = 0; i < 4; ++i) {
      int gr = mtile * 128 + wr * 64 + m * 16 + rq + i;
      if (gr < cnt) {
#pragma unroll
        for (int n = 0; n < 4; ++n) {
          int gc = ntile * 128 + wc * 64 + n * 16 + cl;
          float v = acc[m][n][i] + b1[e * FDIM + gc];
          v = fmaxf(v, 0.f);
          h[(size_t)(off + gr) * FDIM + gc] = f2bf(v);
        }
      }
    }
  }
}

// ---------------- GEMM2: out[t] += w * (h @ W2 + b2) ------------------------
__global__ __launch_bounds__(256) void gemm2_kernel(
    const u16* __restrict__ h, const u16* __restrict__ W2T,
    const float* __restrict__ b2, const int* __restrict__ assignTok,
    const float* __restrict__ assignW, const int* __restrict__ counts,
    const int* __restrict__ offsets, float* __restrict__ out) {
  int e = blockIdx.y;
  int cnt = counts[e];
  int mtile = blockIdx.x & 127, ntile = blockIdx.x >> 7;
  if (mtile * 128 >= cnt) return;
  int off = offsets[e];
  const u16* A = h + (size_t)(off + mtile * 128) * FDIM;
  const u16* B = W2T + ((size_t)e * DDIM + ntile * 128) * FDIM;
  __shared__ u16 As[128 * 32];
  __shared__ u16 Bs[128 * 32];
  f32x4 acc[4][4] = {};
  gemm_mainloop<FDIM>(A, B, As, Bs, acc);
  int lane = threadIdx.x & 63, wave = threadIdx.x >> 6;
  int wr = wave >> 1, wc = wave & 1;
  int cl = lane & 15, rq = (lane >> 4) * 4;
#pragma unroll
  for (int m = 0; m < 4; ++m) {
#pragma unroll
    for (int i = 0; i < 4; ++i) {
      int gr = mtile * 128 + wr * 64 + m * 16 + rq + i;
      if (gr < cnt) {
        int a = off + gr;
        int t = assignTok[a];
        float w = assignW[a];
#pragma unroll
        for (int n = 0; n < 4; ++n) {
          int gc = ntile * 128 + wc * 64 + n * 16 + cl;
          float v = (acc[m][n][i] + b2[e * DDIM + gc]) * w;
          atomicAdd(out + (size_t)t * DDIM + gc, v);
        }
      }
    }
  }
}

extern "C" void kernel_launch(void* const* d_in, const int* in_sizes, int n_in,
                              void* d_out, int out_size, void* d_ws, size_t ws_size,
                              hipStream_t stream) {
  const float* x  = (const float*)d_in[0];
  const float* Wr = (const float*)d_in[1];
  const float* br = (const float*)d_in[2];
  const float* W1 = (const float*)d_in[3];
  const float* b1 = (const float*)d_in[4];
  const float* W2 = (const float*)d_in[5];
  const float* b2 = (const float*)d_in[6];
  float* out = (float*)d_out;

  char* ws = (char*)d_ws;
  size_t p = 0;
  auto alloc = [&](size_t bytes) -> void* {
    void* r = ws + p;
    p = (p + bytes + 255) & ~(size_t)255;
    return r;
  };
  int* counts     = (int*)alloc(ENUM * 4);
  int* offsets    = (int*)alloc(ENUM * 4);
  int* cursor     = (int*)alloc(ENUM * 4);
  int* top2e      = (int*)alloc((size_t)NTOK * 2 * 4);
  float* top2v    = (float*)alloc((size_t)NTOK * 2 * 4);
  int* assignTok  = (int*)alloc((size_t)APAD * 4);
  float* assignW  = (float*)alloc((size_t)APAD * 4);
  float* gatePart = (float*)alloc((size_t)4096 * 8 * 4);
  u16* W1T        = (u16*)alloc((size_t)ENUM * FDIM * DDIM * 2);
  u16* W2T        = (u16*)alloc((size_t)ENUM * DDIM * FDIM * 2);
  u16* Xg         = (u16*)alloc((size_t)APAD * DDIM * 2);
  u16* hbuf       = (u16*)alloc((size_t)APAD * FDIM * 2);
  (void)in_sizes; (void)n_in; (void)out_size; (void)ws_size;  // ~204 MB of ws used

  hipMemsetAsync(d_out, 0, ((size_t)NTOK * DDIM + 1) * 4, stream);
  hipMemsetAsync(counts, 0, ENUM * 4, stream);
  transpose_kernel<<<dim3(256, 8), 256, 0, stream>>>(W1, W1T, DDIM, FDIM);
  transpose_kernel<<<dim3(256, 8), 256, 0, stream>>>(W2, W2T, FDIM, DDIM);
  router_kernel<<<4096, 256, 0, stream>>>(x, Wr, br, top2e, top2v, counts, gatePart);
  finalize_kernel<<<1, 256, 0, stream>>>(counts, offsets, cursor, gatePart,
                                         out + (size_t)NTOK * DDIM);
  place_kernel<<<4096, 256, 0, stream>>>(x, top2e, top2v, cursor, assignTok,
                                         assignW, Xg);
  gemm1_kernel<<<dim3(2048, 8), 256, 0, stream>>>(Xg, W1T, b1, hbuf, counts, offsets);
  gemm2_kernel<<<dim3(512, 8), 256, 0, stream>>>(hbuf, W2T, b2, assignTok, assignW,
                                                 counts, offsets, out);
}

// Round 2
// 428.315 us; speedup vs baseline: 2.7739x; 2.7739x over previous
//
#include <hip/hip_runtime.h>
#include <math.h>

typedef unsigned short u16;
typedef __attribute__((ext_vector_type(8))) short short8;
typedef __attribute__((ext_vector_type(8))) u16 u16x8;
typedef __attribute__((ext_vector_type(4))) float f32x4;

#define NTOK 16384   // B*S
#define DDIM 512
#define FDIM 2048
#define ENUM 8
#define NBLK 1024    // router/place blocks (16 tokens each)
#define APAD (32768 + 256)

__device__ __forceinline__ u16 f2bf(float f) {
  unsigned u = __float_as_uint(f);
  u += 0x7FFFu + ((u >> 16) & 1u);   // RNE
  return (u16)(u >> 16);
}

typedef const __attribute__((address_space(1))) unsigned int* gas1_t;
typedef __attribute__((address_space(3))) unsigned int* las3_t;
__device__ __forceinline__ void gload16(const u16* g, u16* l) {
  __builtin_amdgcn_global_load_lds((gas1_t)(const void*)g, (las3_t)(void*)l, 16, 0, 0);
}

// ---------------- router: logits, softmax, top2; per-block hist/gate --------
__global__ __launch_bounds__(256) void router_kernel(
    const float* __restrict__ x, const float* __restrict__ Wr,
    const float* __restrict__ br, int* __restrict__ top2e,
    float* __restrict__ top2v, int* __restrict__ histBase,
    float* __restrict__ gatePart) {
  __shared__ __align__(16) float sWr[DDIM * ENUM];   // word = d*8+e
  __shared__ __align__(16) float sX[4][DDIM];
  __shared__ int sHist[ENUM];
  __shared__ float sGate[ENUM];
  int tid = threadIdx.x;
  for (int i = tid; i < DDIM * ENUM; i += 256) sWr[i] = Wr[i];
  if (tid < ENUM) { sHist[tid] = 0; sGate[tid] = 0.f; }
  __syncthreads();
  int wave = tid >> 6, lane = tid & 63;
  int e = lane >> 3, dg = lane & 7;
  float bre = br[e];
  for (int it = 0; it < 4; ++it) {
    int t = blockIdx.x * 16 + wave * 4 + it;
    const float4* xr = (const float4*)(x + (size_t)t * DDIM);
    float4* sx4 = (float4*)sX[wave];
    sx4[lane] = xr[lane];
    sx4[lane + 64] = xr[lane + 64];
    asm volatile("s_waitcnt lgkmcnt(0)" ::: "memory");
    float acc = 0.f;
#pragma unroll 16
    for (int i = 0; i < 64; ++i) {
      float xv = sX[wave][i * 8 + dg];                 // 8 banks, 8-way bcast: free
      acc += xv * sWr[(i * 8 + dg) * 8 + e];          // 2-way alias: free
    }
    acc += __shfl_xor(acc, 1);
    acc += __shfl_xor(acc, 2);
    acc += __shfl_xor(acc, 4);
    float logit = acc + bre;
    float m = logit;
    m = fmaxf(m, __shfl_xor(m, 8));
    m = fmaxf(m, __shfl_xor(m, 16));
    m = fmaxf(m, __shfl_xor(m, 32));
    float pv = expf(logit - m);
    float s = pv;
    s += __shfl_xor(s, 8);
    s += __shfl_xor(s, 16);
    s += __shfl_xor(s, 32);
    float gate = pv / s;
    float v1 = gate; int i1 = e;
#pragma unroll
    for (int msk = 8; msk <= 32; msk <<= 1) {
      float ov = __shfl_xor(v1, msk);
      int oi = __shfl_xor(i1, msk);
      if (ov > v1 || (ov == v1 && oi < i1)) { v1 = ov; i1 = oi; }
    }
    float g2 = (e == i1) ? -1.f : gate;
    float v2 = g2; int i2 = e;
#pragma unroll
    for (int msk = 8; msk <= 32; msk <<= 1) {
      float ov = __shfl_xor(v2, msk);
      int oi = __shfl_xor(i2, msk);
      if (ov > v2 || (ov == v2 && oi < i2)) { v2 = ov; i2 = oi; }
    }
    if (lane == 0) {
      top2e[2 * t] = i1; top2e[2 * t + 1] = i2;
      top2v[2 * t] = v1; top2v[2 * t + 1] = v2;
      atomicAdd(&sHist[i1], 1);
      atomicAdd(&sHist[i2], 1);
    }
    if (dg == 0) atomicAdd(&sGate[e], gate);
  }
  __syncthreads();
  if (tid < ENUM) {
    histBase[blockIdx.x * 8 + tid] = sHist[tid];
    gatePart[blockIdx.x * 8 + tid] = sGate[tid];
  }
}

// ---------------- scan: hist -> exclusive block bases, offsets, aux ---------
__global__ __launch_bounds__(256) void scan_kernel(
    int* __restrict__ histBase, const float* __restrict__ gatePart,
    int* __restrict__ offsets, int* __restrict__ counts,
    float* __restrict__ auxOut) {
  __shared__ int sTot[ENUM];
  __shared__ float sG[ENUM];
  int tid = threadIdx.x, wave = tid >> 6, lane = tid & 63;
  if (tid < ENUM) sG[tid] = 0.f;
  __syncthreads();
  float loc[8] = {0, 0, 0, 0, 0, 0, 0, 0};
  for (int r = tid; r < NBLK; r += 256) {
#pragma unroll
    for (int e = 0; e < 8; ++e) loc[e] += gatePart[r * 8 + e];
  }
#pragma unroll
  for (int e = 0; e < 8; ++e) atomicAdd(&sG[e], loc[e]);
  // per-expert exclusive prefix over NBLK blocks; wave w owns experts 2w,2w+1
#pragma unroll
  for (int ei = 0; ei < 2; ++ei) {
    int e = wave * 2 + ei;
    int running = 0;
    for (int itb = 0; itb < NBLK / 64; ++itb) {
      int idx = (itb * 64 + lane) * 8 + e;
      int v = histBase[idx];
      int inc = v;
#pragma unroll
      for (int d = 1; d < 64; d <<= 1) {
        int o = __shfl_up(inc, d);
        if (lane >= d) inc += o;
      }
      histBase[idx] = running + inc - v;   // exclusive base for this block
      running += __shfl(inc, 63);
    }
    if (lane == 0) sTot[e] = running;
  }
  __syncthreads();
  if (tid == 0) {
    int off = 0;
#pragma unroll
    for (int e = 0; e < 8; ++e) {
      offsets[e] = off; counts[e] = sTot[e]; off += sTot[e];
    }
    float aux = 0.f;
#pragma unroll
    for (int e = 0; e < 8; ++e) {
      float pr = sG[e] / (float)NTOK;
      aux += pr * logf(pr + 1e-9f);
    }
    *auxOut = aux;
  }
}

// ---------------- place: deterministic ranks + gathered bf16 X --------------
__global__ __launch_bounds__(256) void place_kernel(
    const float* __restrict__ x, const int* __restrict__ top2e,
    const float* __restrict__ top2v, const int* __restrict__ histBase,
    const int* __restrict__ offsets, int* __restrict__ assignTok,
    float* __restrict__ assignW, u16* __restrict__ Xg) {
  __shared__ int sA[32];
  int tid = threadIdx.x, wave = tid >> 6, lane = tid & 63;
  int blk = blockIdx.x;
  if (tid < 32) {
    int slot = tid;
    int t = blk * 16 + (slot >> 1);
    int e = top2e[2 * t + (slot & 1)];
    float v = top2v[2 * t + (slot & 1)];
    int rank = 0;
#pragma unroll
    for (int ee = 0; ee < 8; ++ee) {
      unsigned long long mm = __ballot(e == ee);
      if (e == ee) rank = __popcll(mm & ((1ull << slot) - 1));
    }
    int a = offsets[e] + histBase[blk * 8 + e] + rank;
    sA[slot] = a;
    assignTok[a] = t;
    assignW[a] = v;
  }
  __syncthreads();
  for (int it = 0; it < 4; ++it) {
    int lt = wave * 4 + it;
    int t = blk * 16 + lt;
    const float4* xr = (const float4*)(x + (size_t)t * DDIM);
    float4 v0 = xr[lane * 2], v1 = xr[lane * 2 + 1];
    u16x8 o;
    o[0] = f2bf(v0.x); o[1] = f2bf(v0.y); o[2] = f2bf(v0.z); o[3] = f2bf(v0.w);
    o[4] = f2bf(v1.x); o[5] = f2bf(v1.y); o[6] = f2bf(v1.z); o[7] = f2bf(v1.w);
    int a1 = sA[2 * lt], a2 = sA[2 * lt + 1];
    *(u16x8*)(Xg + (size_t)a1 * DDIM + lane * 8) = o;
    *(u16x8*)(Xg + (size_t)a2 * DDIM + lane * 8) = o;
  }
}

// ---------------- weight transpose+convert: [K][N] f32 -> [N][K] bf16 -------
__global__ __launch_bounds__(256) void transpose_kernel(
    const float* __restrict__ W, u16* __restrict__ WT, int K, int N) {
  __shared__ float tile[64][65];
  int e = blockIdx.y;
  int tn_count = N >> 6;
  int tk = blockIdx.x / tn_count;
  int tn = blockIdx.x - tk * tn_count;
  const float* Wp = W + (size_t)e * K * N;
  u16* WTp = WT + (size_t)e * N * K;
  int c = threadIdx.x & 63, r = threadIdx.x >> 6;
#pragma unroll
  for (int i = 0; i < 16; ++i) {
    int row = r + i * 4;
    tile[row][c] = Wp[(size_t)(tk * 64 + row) * N + tn * 64 + c];
  }
  __syncthreads();
#pragma unroll
  for (int i = 0; i < 16; ++i) {
    int row = r + i * 4;
    WTp[(size_t)(tn * 64 + row) * K + tk * 64 + c] = f2bf(tile[c][row]);
  }
}

// ---------------- GEMM mainloop: 128x128 tile, BK=32, global_load_lds -------
// LDS layout [128][32] bf16 with per-row XOR slot swizzle (both-sides, m173).
template <int K>
__device__ __forceinline__ void gemm_mainloop(const u16* __restrict__ A,
                                              const u16* __restrict__ B,
                                              u16* As, u16* Bs,
                                              f32x4 (&acc)[4][4]) {
  int tid = threadIdx.x;
  int wave = tid >> 6, lane = tid & 63;
  int wr = wave >> 1, wc = wave & 1;
  int c0 = tid, c1 = tid + 256;
  int r0 = c0 >> 2, r1 = c1 >> 2;
  int f0 = (r0 ^ (r0 >> 2)) & 3;            // same for r1 (=r0+64)
  int k0c = ((c0 & 3) ^ f0) * 8;
  int k1c = ((c1 & 3) ^ f0) * 8;
  const u16* Ag0 = A + (size_t)r0 * K + k0c;
  const u16* Ag1 = A + (size_t)r1 * K + k1c;
  const u16* Bg0 = B + (size_t)r0 * K + k0c;
  const u16* Bg1 = B + (size_t)r1 * K + k1c;
  u16* As0 = As + wave * 512;               // wave-uniform LDS bases
  u16* As1 = As + 2048 + wave * 512;
  u16* Bs0 = Bs + wave * 512;
  u16* Bs1 = Bs + 2048 + wave * 512;
  int fr = lane & 15;
  int sw = (fr ^ (fr >> 2)) & 3;
  int slot = (lane >> 4) ^ sw;              // swizzled k-slot on read
  const u16* Af = As + (size_t)(wr * 64 + fr) * 32 + slot * 8;
  const u16* Bf = Bs + (size_t)(wc * 64 + fr) * 32 + slot * 8;
  for (int k0 = 0; k0 < K; k0 += 32) {
    __syncthreads();                         // LDS safe to overwrite
    gload16(Ag0 + k0, As0);
    gload16(Ag1 + k0, As1);
    gload16(Bg0 + k0, Bs0);
    gload16(Bg1 + k0, Bs1);
    __syncthreads();                         // vmcnt(0) drained by barrier
    short8 af[4], bf[4];
#pragma unroll
    for (int m = 0; m < 4; ++m) af[m] = *(const short8*)(Af + m * 512);
#pragma unroll
    for (int n = 0; n < 4; ++n) bf[n] = *(const short8*)(Bf + n * 512);
#pragma unroll
    for (int m = 0; m < 4; ++m)
#pragma unroll
      for (int n = 0; n < 4; ++n)
        acc[m][n] = __builtin_amdgcn_mfma_f32_16x16x32_bf16(af[m], bf[n],
                                                            acc[m][n], 0, 0, 0);
  }
}

// ---------------- GEMM1: h = relu(Xg @ W1 + b1), bf16 out -------------------
__global__ __launch_bounds__(256) void gemm1_kernel(
    const u16* __restrict__ Xg, const u16* __restrict__ W1T,
    const float* __restrict__ b1, u16* __restrict__ h,
    const int* __restrict__ counts, const int* __restrict__ offsets) {
  int e = blockIdx.y;
  int cnt = counts[e];
  int mtile = blockIdx.x & 127, ntile = blockIdx.x >> 7;
  if (mtile * 128 >= cnt) return;
  int off = offsets[e];
  const u16* A = Xg + (size_t)(off + mtile * 128) * DDIM;
  const u16* B = W1T + ((size_t)e * FDIM + ntile * 128) * DDIM;
  __shared__ __align__(16) u16 As[128 * 32];
  __shared__ __align__(16) u16 Bs[128 * 32];
  f32x4 acc[4][4] = {};
  gemm_mainloop<DDIM>(A, B, As, Bs, acc);
  int lane = threadIdx.x & 63, wave = threadIdx.x >> 6;
  int wr = wave >> 1, wc = wave & 1;
  int cl = lane & 15, rq = (lane >> 4) * 4;
#pragma unroll
  for (int m = 0; m < 4; ++m) {
#pragma unroll
    for (int i = 0; i < 4; ++i) {
      int gr = mtile * 128 + wr * 64 + m * 16 + rq + i;
      if (gr < cnt) {
#pragma unroll
        for (int n = 0; n < 4; ++n) {
          int gc = ntile * 128 + wc * 64 + n * 16 + cl;
          float v = acc[m][n][i] + b1[e * FDIM + gc];
          v = fmaxf(v, 0.f);
          h[(size_t)(off + gr) * FDIM + gc] = f2bf(v);
        }
      }
    }
  }
}

// ---------------- GEMM2: out[t] += w * (h @ W2 + b2) ------------------------
__global__ __launch_bounds__(256) void gemm2_kernel(
    const u16* __restrict__ h, const u16* __restrict__ W2T,
    const float* __restrict__ b2, const int* __restrict__ assignTok,
    const float* __restrict__ assignW, const int* __restrict__ counts,
    const int* __restrict__ offsets, float* __restrict__ out) {
  int e = blockIdx.y;
  int cnt = counts[e];
  int mtile = blockIdx.x & 127, ntile = blockIdx.x >> 7;
  if (mtile * 128 >= cnt) return;
  int off = offsets[e];
  const u16* A = h + (size_t)(off + mtile * 128) * FDIM;
  const u16* B = W2T + ((size_t)e * DDIM + ntile * 128) * FDIM;
  __shared__ __align__(16) u16 As[128 * 32];
  __shared__ __align__(16) u16 Bs[128 * 32];
  f32x4 acc[4][4] = {};
  gemm_mainloop<FDIM>(A, B, As, Bs, acc);
  int lane = threadIdx.x & 63, wave = threadIdx.x >> 6;
  int wr = wave >> 1, wc = wave & 1;
  int cl = lane & 15, rq = (lane >> 4) * 4;
#pragma unroll
  for (int m = 0; m < 4; ++m) {
#pragma unroll
    for (int i = 0; i < 4; ++i) {
      int gr = mtile * 128 + wr * 64 + m * 16 + rq + i;
      if (gr < cnt) {
        int a = off + gr;
        int t = assignTok[a];
        float w = assignW[a];
#pragma unroll
        for (int n = 0; n < 4; ++n) {
          int gc = ntile * 128 + wc * 64 + n * 16 + cl;
          float v = (acc[m][n][i] + b2[e * DDIM + gc]) * w;
          atomicAdd(out + (size_t)t * DDIM + gc, v);
        }
      }
    }
  }
}

extern "C" void kernel_launch(void* const* d_in, const int* in_sizes, int n_in,
                              void* d_out, int out_size, void* d_ws, size_t ws_size,
                              hipStream_t stream) {
  const float* x  = (const float*)d_in[0];
  const float* Wr = (const float*)d_in[1];
  const float* br = (const float*)d_in[2];
  const float* W1 = (const float*)d_in[3];
  const float* b1 = (const float*)d_in[4];
  const float* W2 = (const float*)d_in[5];
  const float* b2 = (const float*)d_in[6];
  float* out = (float*)d_out;

  char* ws = (char*)d_ws;
  size_t p = 0;
  auto alloc = [&](size_t bytes) -> void* {
    void* r = ws + p;
    p = (p + bytes + 255) & ~(size_t)255;
    return r;
  };
  int* counts     = (int*)alloc(ENUM * 4);
  int* offsets    = (int*)alloc(ENUM * 4);
  int* top2e      = (int*)alloc((size_t)NTOK * 2 * 4);
  float* top2v    = (float*)alloc((size_t)NTOK * 2 * 4);
  int* assignTok  = (int*)alloc((size_t)APAD * 4);
  float* assignW  = (float*)alloc((size_t)APAD * 4);
  int* histBase   = (int*)alloc((size_t)NBLK * 8 * 4);
  float* gatePart = (float*)alloc((size_t)NBLK * 8 * 4);
  u16* W1T        = (u16*)alloc((size_t)ENUM * FDIM * DDIM * 2);
  u16* W2T        = (u16*)alloc((size_t)ENUM * DDIM * FDIM * 2);
  u16* Xg         = (u16*)alloc((size_t)APAD * DDIM * 2);
  u16* hbuf       = (u16*)alloc((size_t)APAD * FDIM * 2);
  (void)in_sizes; (void)n_in; (void)out_size; (void)ws_size;  // ~203 MB used

  hipMemsetAsync(d_out, 0, ((size_t)NTOK * DDIM + 1) * 4, stream);
  transpose_kernel<<<dim3(256, 8), 256, 0, stream>>>(W1, W1T, DDIM, FDIM);
  transpose_kernel<<<dim3(256, 8), 256, 0, stream>>>(W2, W2T, FDIM, DDIM);
  router_kernel<<<NBLK, 256, 0, stream>>>(x, Wr, br, top2e, top2v, histBase,
                                          gatePart);
  scan_kernel<<<1, 256, 0, stream>>>(histBase, gatePart, offsets, counts,
                                     out + (size_t)NTOK * DDIM);
  place_kernel<<<NBLK, 256, 0, stream>>>(x, top2e, top2v, histBase, offsets,
                                         assignTok, assignW, Xg);
  gemm1_kernel<<<dim3(2048, 8), 256, 0, stream>>>(Xg, W1T, b1, hbuf, counts,
                                                  offsets);
  gemm2_kernel<<<dim3(512, 8), 256, 0, stream>>>(hbuf, W2T, b2, assignTok,
                                                 assignW, counts, offsets, out);
}

// Round 3
// 347.987 us; speedup vs baseline: 3.4143x; 1.2308x over previous
//
#include <hip/hip_runtime.h>
#include <math.h>

typedef unsigned short u16;
typedef __attribute__((ext_vector_type(8))) short short8;
typedef __attribute__((ext_vector_type(8))) u16 u16x8;
typedef __attribute__((ext_vector_type(4))) float f32x4;

#define NTOK 16384   // B*S
#define DDIM 512
#define FDIM 2048
#define ENUM 8
#define NBLK 1024    // router/place blocks (16 tokens each)
#define APAD (32768 + 256)
#define MAXTILES 264 // sum ceil(cnt_e/128) <= 256 + 8

__device__ __forceinline__ u16 f2bf(float f) {
  unsigned u = __float_as_uint(f);
  u += 0x7FFFu + ((u >> 16) & 1u);   // RNE
  return (u16)(u >> 16);
}
__device__ __forceinline__ float bf2f(u16 b) {
  return __uint_as_float(((unsigned)b) << 16);
}

typedef const __attribute__((address_space(1))) unsigned int* gas1_t;
typedef __attribute__((address_space(3))) unsigned int* las3_t;
__device__ __forceinline__ void gload16(const u16* g, u16* l) {
  __builtin_amdgcn_global_load_lds((gas1_t)(const void*)g, (las3_t)(void*)l, 16, 0, 0);
}

// ---------------- router: logits, softmax, top2; per-block hist/gate --------
__global__ __launch_bounds__(256) void router_kernel(
    const float* __restrict__ x, const float* __restrict__ Wr,
    const float* __restrict__ br, int* __restrict__ top2e,
    float* __restrict__ top2v, int* __restrict__ histBase,
    float* __restrict__ gatePart) {
  __shared__ __align__(16) float sWr[DDIM * ENUM];   // word = d*8+e
  __shared__ __align__(16) float sX[4][DDIM];
  __shared__ int sHist[ENUM];
  __shared__ float sGate[ENUM];
  int tid = threadIdx.x;
  for (int i = tid; i < DDIM * ENUM; i += 256) sWr[i] = Wr[i];
  if (tid < ENUM) { sHist[tid] = 0; sGate[tid] = 0.f; }
  __syncthreads();
  int wave = tid >> 6, lane = tid & 63;
  int e = lane >> 3, dg = lane & 7;
  float bre = br[e];
  for (int it = 0; it < 4; ++it) {
    int t = blockIdx.x * 16 + wave * 4 + it;
    const float4* xr = (const float4*)(x + (size_t)t * DDIM);
    float4* sx4 = (float4*)sX[wave];
    sx4[lane] = xr[lane];
    sx4[lane + 64] = xr[lane + 64];
    asm volatile("s_waitcnt lgkmcnt(0)" ::: "memory");
    float acc = 0.f;
#pragma unroll 16
    for (int i = 0; i < 64; ++i) {
      float xv = sX[wave][i * 8 + dg];
      acc += xv * sWr[(i * 8 + dg) * 8 + e];
    }
    acc += __shfl_xor(acc, 1);
    acc += __shfl_xor(acc, 2);
    acc += __shfl_xor(acc, 4);
    float logit = acc + bre;
    float m = logit;
    m = fmaxf(m, __shfl_xor(m, 8));
    m = fmaxf(m, __shfl_xor(m, 16));
    m = fmaxf(m, __shfl_xor(m, 32));
    float pv = expf(logit - m);
    float s = pv;
    s += __shfl_xor(s, 8);
    s += __shfl_xor(s, 16);
    s += __shfl_xor(s, 32);
    float gate = pv / s;
    float v1 = gate; int i1 = e;
#pragma unroll
    for (int msk = 8; msk <= 32; msk <<= 1) {
      float ov = __shfl_xor(v1, msk);
      int oi = __shfl_xor(i1, msk);
      if (ov > v1 || (ov == v1 && oi < i1)) { v1 = ov; i1 = oi; }
    }
    float g2 = (e == i1) ? -1.f : gate;
    float v2 = g2; int i2 = e;
#pragma unroll
    for (int msk = 8; msk <= 32; msk <<= 1) {
      float ov = __shfl_xor(v2, msk);
      int oi = __shfl_xor(i2, msk);
      if (ov > v2 || (ov == v2 && oi < i2)) { v2 = ov; i2 = oi; }
    }
    if (lane == 0) {
      top2e[2 * t] = i1; top2e[2 * t + 1] = i2;
      top2v[2 * t] = v1; top2v[2 * t + 1] = v2;
      atomicAdd(&sHist[i1], 1);
      atomicAdd(&sHist[i2], 1);
    }
    if (dg == 0) atomicAdd(&sGate[e], gate);
  }
  __syncthreads();
  if (tid < ENUM) {
    histBase[blockIdx.x * 8 + tid] = sHist[tid];
    gatePart[blockIdx.x * 8 + tid] = sGate[tid];
  }
}

// ---------------- scan: bases, offsets, tile table, aux ---------------------
__global__ __launch_bounds__(256) void scan_kernel(
    int* __restrict__ histBase, const float* __restrict__ gatePart,
    int* __restrict__ offsets, int* __restrict__ counts,
    int* __restrict__ tileE, int* __restrict__ tileM, int* __restrict__ nTiles,
    float* __restrict__ auxOut) {
  __shared__ int sTot[ENUM];
  __shared__ float sG[ENUM];
  int tid = threadIdx.x, wave = tid >> 6, lane = tid & 63;
  if (tid < ENUM) sG[tid] = 0.f;
  __syncthreads();
  float loc[8] = {0, 0, 0, 0, 0, 0, 0, 0};
  for (int r = tid; r < NBLK; r += 256) {
#pragma unroll
    for (int e = 0; e < 8; ++e) loc[e] += gatePart[r * 8 + e];
  }
#pragma unroll
  for (int e = 0; e < 8; ++e) atomicAdd(&sG[e], loc[e]);
#pragma unroll
  for (int ei = 0; ei < 2; ++ei) {
    int e = wave * 2 + ei;
    int running = 0;
    for (int itb = 0; itb < NBLK / 64; ++itb) {
      int idx = (itb * 64 + lane) * 8 + e;
      int v = histBase[idx];
      int inc = v;
#pragma unroll
      for (int d = 1; d < 64; d <<= 1) {
        int o = __shfl_up(inc, d);
        if (lane >= d) inc += o;
      }
      histBase[idx] = running + inc - v;
      running += __shfl(inc, 63);
    }
    if (lane == 0) sTot[e] = running;
  }
  __syncthreads();
  if (tid == 0) {
    int off = 0, nt = 0;
#pragma unroll
    for (int e = 0; e < 8; ++e) {
      int c = sTot[e];
      offsets[e] = off; counts[e] = c; off += c;
      int mt = (c + 127) >> 7;
      for (int m = 0; m < mt; ++m) { tileE[nt] = e; tileM[nt] = m; ++nt; }
    }
    *nTiles = nt;
    float aux = 0.f;
#pragma unroll
    for (int e = 0; e < 8; ++e) {
      float pr = sG[e] / (float)NTOK;
      aux += pr * logf(pr + 1e-9f);
    }
    *auxOut = aux;
  }
}

// ---------------- place: deterministic ranks + gathered bf16 X + tokA -------
__global__ __launch_bounds__(256) void place_kernel(
    const float* __restrict__ x, const int* __restrict__ top2e,
    const float* __restrict__ top2v, const int* __restrict__ histBase,
    const int* __restrict__ offsets, int* __restrict__ tokA,
    float* __restrict__ assignW, u16* __restrict__ Xg) {
  __shared__ int sA[32];
  int tid = threadIdx.x, wave = tid >> 6, lane = tid & 63;
  int blk = blockIdx.x;
  if (tid < 32) {
    int slot = tid;
    int t = blk * 16 + (slot >> 1);
    int e = top2e[2 * t + (slot & 1)];
    float v = top2v[2 * t + (slot & 1)];
    int rank = 0;
#pragma unroll
    for (int ee = 0; ee < 8; ++ee) {
      unsigned long long mm = __ballot(e == ee);
      if (e == ee) rank = __popcll(mm & ((1ull << slot) - 1));
    }
    int a = offsets[e] + histBase[blk * 8 + e] + rank;
    sA[slot] = a;
    tokA[2 * t + (slot & 1)] = a;
    assignW[a] = v;
  }
  __syncthreads();
  for (int it = 0; it < 4; ++it) {
    int lt = wave * 4 + it;
    int t = blk * 16 + lt;
    const float4* xr = (const float4*)(x + (size_t)t * DDIM);
    float4 v0 = xr[lane * 2], v1 = xr[lane * 2 + 1];
    u16x8 o;
    o[0] = f2bf(v0.x); o[1] = f2bf(v0.y); o[2] = f2bf(v0.z); o[3] = f2bf(v0.w);
    o[4] = f2bf(v1.x); o[5] = f2bf(v1.y); o[6] = f2bf(v1.z); o[7] = f2bf(v1.w);
    int a1 = sA[2 * lt], a2 = sA[2 * lt + 1];
    *(u16x8*)(Xg + (size_t)a1 * DDIM + lane * 8) = o;
    *(u16x8*)(Xg + (size_t)a2 * DDIM + lane * 8) = o;
  }
}

// ---------------- weight transpose+convert: [K][N] f32 -> [N][K] bf16 -------
__global__ __launch_bounds__(256) void transpose_kernel(
    const float* __restrict__ W, u16* __restrict__ WT, int K, int N) {
  __shared__ float tile[64][65];
  int e = blockIdx.y;
  int tn_count = N >> 6;
  int tk = blockIdx.x / tn_count;
  int tn = blockIdx.x - tk * tn_count;
  const float* Wp = W + (size_t)e * K * N;
  u16* WTp = WT + (size_t)e * N * K;
  int c = threadIdx.x & 63, r = threadIdx.x >> 6;
#pragma unroll
  for (int i = 0; i < 16; ++i) {
    int row = r + i * 4;
    tile[row][c] = Wp[(size_t)(tk * 64 + row) * N + tn * 64 + c];
  }
  __syncthreads();
#pragma unroll
  for (int i = 0; i < 16; ++i) {
    int row = r + i * 4;
    WTp[(size_t)(tn * 64 + row) * K + tk * 64 + c] = f2bf(tile[c][row]);
  }
}

// ---------------- GEMM mainloop: 128x128, BK=32, 2-phase dbuf pipeline ------
// LDS [2][128][32] per operand; XOR k-slot swizzle applied on BOTH the global
// source address (pre-swizzle, m173) and the fragment read (same involution).
template <int K>
__device__ __forceinline__ void gemm_mainloop(const u16* __restrict__ A,
                                              const u16* __restrict__ B,
                                              u16* As, u16* Bs,
                                              f32x4 (&acc)[4][4]) {
  int tid = threadIdx.x;
  int wave = tid >> 6, lane = tid & 63;
  int wr = wave >> 1, wc = wave & 1;
  int c0 = tid, c1 = tid + 256;
  int r0 = c0 >> 2, r1 = c1 >> 2;
  int f0 = (r0 ^ (r0 >> 2)) & 3;            // same for r1 (=r0+64)
  int k0c = ((c0 & 3) ^ f0) * 8;
  int k1c = ((c1 & 3) ^ f0) * 8;
  const u16* Ag0 = A + (size_t)r0 * K + k0c;
  const u16* Ag1 = A + (size_t)r1 * K + k1c;
  const u16* Bg0 = B + (size_t)r0 * K + k0c;
  const u16* Bg1 = B + (size_t)r1 * K + k1c;
  int wb = wave * 512;                       // wave-uniform LDS base (u16)
  int fr = lane & 15;
  int sw = (fr ^ (fr >> 2)) & 3;
  int slot = (lane >> 4) ^ sw;
  int fA = (wr * 64 + fr) * 32 + slot * 8;
  int fB = (wc * 64 + fr) * 32 + slot * 8;

  // prologue: stage tile 0 into buffer 0
  gload16(Ag0, As + wb);
  gload16(Ag1, As + 2048 + wb);
  gload16(Bg0, Bs + wb);
  gload16(Bg1, Bs + 2048 + wb);
  __syncthreads();
  int cur = 0;
  for (int k0 = 32; k0 < K; k0 += 32) {
    int nb = (cur ^ 1) * 4096;
    gload16(Ag0 + k0, As + nb + wb);         // issue next tile's loads first
    gload16(Ag1 + k0, As + nb + 2048 + wb);
    gload16(Bg0 + k0, Bs + nb + wb);
    gload16(Bg1 + k0, Bs + nb + 2048 + wb);
    const u16* Ac = As + cur * 4096;
    const u16* Bc = Bs + cur * 4096;
    short8 af[4], bf[4];
#pragma unroll
    for (int m = 0; m < 4; ++m) af[m] = *(const short8*)(Ac + fA + m * 512);
#pragma unroll
    for (int n = 0; n < 4; ++n) bf[n] = *(const short8*)(Bc + fB + n * 512);
#pragma unroll
    for (int m = 0; m < 4; ++m)
#pragma unroll
      for (int n = 0; n < 4; ++n)
        acc[m][n] = __builtin_amdgcn_mfma_f32_16x16x32_bf16(af[m], bf[n],
                                                            acc[m][n], 0, 0, 0);
    __syncthreads();                         // drains vmcnt: next buf ready
    cur ^= 1;
  }
  const u16* Ac = As + cur * 4096;
  const u16* Bc = Bs + cur * 4096;
  short8 af[4], bf[4];
#pragma unroll
  for (int m = 0; m < 4; ++m) af[m] = *(const short8*)(Ac + fA + m * 512);
#pragma unroll
  for (int n = 0; n < 4; ++n) bf[n] = *(const short8*)(Bc + fB + n * 512);
#pragma unroll
  for (int m = 0; m < 4; ++m)
#pragma unroll
    for (int n = 0; n < 4; ++n)
      acc[m][n] = __builtin_amdgcn_mfma_f32_16x16x32_bf16(af[m], bf[n],
                                                          acc[m][n], 0, 0, 0);
}

// ---------------- GEMM1: h = relu(Xg @ W1 + b1), bf16 out -------------------
__global__ __launch_bounds__(256) void gemm1_kernel(
    const u16* __restrict__ Xg, const u16* __restrict__ W1T,
    const float* __restrict__ b1, u16* __restrict__ h,
    const int* __restrict__ counts, const int* __restrict__ offsets,
    const int* __restrict__ tileE, const int* __restrict__ tileM,
    const int* __restrict__ nTiles) {
  if ((int)blockIdx.x >= *nTiles) return;
  int e = tileE[blockIdx.x], mtile = tileM[blockIdx.x];
  int ntile = blockIdx.y;
  int cnt = counts[e], off = offsets[e];
  const u16* A = Xg + (size_t)(off + mtile * 128) * DDIM;
  const u16* B = W1T + ((size_t)e * FDIM + ntile * 128) * DDIM;
  __shared__ __align__(16) u16 As[2 * 128 * 32];
  __shared__ __align__(16) u16 Bs[2 * 128 * 32];
  f32x4 acc[4][4] = {};
  gemm_mainloop<DDIM>(A, B, As, Bs, acc);
  int lane = threadIdx.x & 63, wave = threadIdx.x >> 6;
  int wr = wave >> 1, wc = wave & 1;
  int cl = lane & 15, rq = (lane >> 4) * 4;
#pragma unroll
  for (int m = 0; m < 4; ++m) {
#pragma unroll
    for (int i = 0; i < 4; ++i) {
      int gr = mtile * 128 + wr * 64 + m * 16 + rq + i;
      if (gr < cnt) {
#pragma unroll
        for (int n = 0; n < 4; ++n) {
          int gc = ntile * 128 + wc * 64 + n * 16 + cl;
          float v = acc[m][n][i] + b1[e * FDIM + gc];
          v = fmaxf(v, 0.f);
          h[(size_t)(off + gr) * FDIM + gc] = f2bf(v);
        }
      }
    }
  }
}

// ---------------- GEMM2: z[a] = w_a * (h @ W2 + b2), bf16 -------------------
__global__ __launch_bounds__(256) void gemm2_kernel(
    const u16* __restrict__ h, const u16* __restrict__ W2T,
    const float* __restrict__ b2, const float* __restrict__ assignW,
    const int* __restrict__ counts, const int* __restrict__ offsets,
    const int* __restrict__ tileE, const int* __restrict__ tileM,
    const int* __restrict__ nTiles, u16* __restrict__ z) {
  if ((int)blockIdx.x >= *nTiles) return;
  int e = tileE[blockIdx.x], mtile = tileM[blockIdx.x];
  int ntile = blockIdx.y;
  int cnt = counts[e], off = offsets[e];
  const u16* A = h + (size_t)(off + mtile * 128) * FDIM;
  const u16* B = W2T + ((size_t)e * DDIM + ntile * 128) * FDIM;
  __shared__ __align__(16) u16 As[2 * 128 * 32];
  __shared__ __align__(16) u16 Bs[2 * 128 * 32];
  f32x4 acc[4][4] = {};
  gemm_mainloop<FDIM>(A, B, As, Bs, acc);
  int lane = threadIdx.x & 63, wave = threadIdx.x >> 6;
  int wr = wave >> 1, wc = wave & 1;
  int cl = lane & 15, rq = (lane >> 4) * 4;
#pragma unroll
  for (int m = 0; m < 4; ++m) {
#pragma unroll
    for (int i = 0; i < 4; ++i) {
      int gr = mtile * 128 + wr * 64 + m * 16 + rq + i;
      if (gr < cnt) {
        int a = off + gr;
        float w = assignW[a];
#pragma unroll
        for (int n = 0; n < 4; ++n) {
          int gc = ntile * 128 + wc * 64 + n * 16 + cl;
          float v = (acc[m][n][i] + b2[e * DDIM + gc]) * w;
          z[(size_t)a * DDIM + gc] = f2bf(v);
        }
      }
    }
  }
}

// ---------------- combine: out[t] = z[a1(t)] + z[a2(t)] ---------------------
__global__ __launch_bounds__(256) void combine_kernel(
    const u16* __restrict__ z, const int* __restrict__ tokA,
    float* __restrict__ out) {
  int tid = threadIdx.x, wave = tid >> 6, lane = tid & 63;
  int t = blockIdx.x * 4 + wave;
  int a1 = tokA[2 * t], a2 = tokA[2 * t + 1];
  u16x8 v1 = *(const u16x8*)(z + (size_t)a1 * DDIM + lane * 8);
  u16x8 v2 = *(const u16x8*)(z + (size_t)a2 * DDIM + lane * 8);
  float4 o0, o1;
  o0.x = bf2f(v1[0]) + bf2f(v2[0]);
  o0.y = bf2f(v1[1]) + bf2f(v2[1]);
  o0.z = bf2f(v1[2]) + bf2f(v2[2]);
  o0.w = bf2f(v1[3]) + bf2f(v2[3]);
  o1.x = bf2f(v1[4]) + bf2f(v2[4]);
  o1.y = bf2f(v1[5]) + bf2f(v2[5]);
  o1.z = bf2f(v1[6]) + bf2f(v2[6]);
  o1.w = bf2f(v1[7]) + bf2f(v2[7]);
  float4* o = (float4*)(out + (size_t)t * DDIM + lane * 8);
  o[0] = o0;
  o[1] = o1;
}

extern "C" void kernel_launch(void* const* d_in, const int* in_sizes, int n_in,
                              void* d_out, int out_size, void* d_ws, size_t ws_size,
                              hipStream_t stream) {
  const float* x  = (const float*)d_in[0];
  const float* Wr = (const float*)d_in[1];
  const float* br = (const float*)d_in[2];
  const float* W1 = (const float*)d_in[3];
  const float* b1 = (const float*)d_in[4];
  const float* W2 = (const float*)d_in[5];
  const float* b2 = (const float*)d_in[6];
  float* out = (float*)d_out;

  char* ws = (char*)d_ws;
  size_t p = 0;
  auto alloc = [&](size_t bytes) -> void* {
    void* r = ws + p;
    p = (p + bytes + 255) & ~(size_t)255;
    return r;
  };
  int* counts     = (int*)alloc(ENUM * 4);
  int* offsets    = (int*)alloc(ENUM * 4);
  int* nTiles     = (int*)alloc(4);
  int* tileE      = (int*)alloc(MAXTILES * 4);
  int* tileM      = (int*)alloc(MAXTILES * 4);
  int* top2e      = (int*)alloc((size_t)NTOK * 2 * 4);
  float* top2v    = (float*)alloc((size_t)NTOK * 2 * 4);
  int* tokA       = (int*)alloc((size_t)NTOK * 2 * 4);
  float* assignW  = (float*)alloc((size_t)APAD * 4);
  int* histBase   = (int*)alloc((size_t)NBLK * 8 * 4);
  float* gatePart = (float*)alloc((size_t)NBLK * 8 * 4);
  u16* W1T        = (u16*)alloc((size_t)ENUM * FDIM * DDIM * 2);
  u16* W2T        = (u16*)alloc((size_t)ENUM * DDIM * FDIM * 2);
  u16* Xg         = (u16*)alloc((size_t)APAD * DDIM * 2);
  u16* hbuf       = (u16*)alloc((size_t)APAD * FDIM * 2);
  u16* z          = Xg;   // alias: Xg is dead after gemm1, z is same size
  (void)in_sizes; (void)n_in; (void)out_size; (void)ws_size;  // ~203 MB used

  transpose_kernel<<<dim3(256, 8), 256, 0, stream>>>(W1, W1T, DDIM, FDIM);
  transpose_kernel<<<dim3(256, 8), 256, 0, stream>>>(W2, W2T, FDIM, DDIM);
  router_kernel<<<NBLK, 256, 0, stream>>>(x, Wr, br, top2e, top2v, histBase,
                                          gatePart);
  scan_kernel<<<1, 256, 0, stream>>>(histBase, gatePart, offsets, counts,
                                     tileE, tileM, nTiles,
                                     out + (size_t)NTOK * DDIM);
  place_kernel<<<NBLK, 256, 0, stream>>>(x, top2e, top2v, histBase, offsets,
                                         tokA, assignW, Xg);
  gemm1_kernel<<<dim3(MAXTILES, 16), 256, 0, stream>>>(
      Xg, W1T, b1, hbuf, counts, offsets, tileE, tileM, nTiles);
  gemm2_kernel<<<dim3(MAXTILES, 4), 256, 0, stream>>>(
      hbuf, W2T, b2, assignW, counts, offsets, tileE, tileM, nTiles, z);
  combine_kernel<<<NTOK / 4, 256, 0, stream>>>(z, tokA, out);
}

// Round 4
// 327.755 us; speedup vs baseline: 3.6250x; 1.0617x over previous
//
#include <hip/hip_runtime.h>
#include <math.h>

typedef unsigned short u16;
typedef __attribute__((ext_vector_type(8))) short short8;
typedef __attribute__((ext_vector_type(8))) u16 u16x8;
typedef __attribute__((ext_vector_type(4))) float f32x4;

#define NTOK 16384   // B*S
#define DDIM 512
#define FDIM 2048
#define ENUM 8
#define NBLK 1024    // router/place blocks (16 tokens each)
#define APAD (32768 + 256)
#define MAXT 144     // sum ceil(cnt_e/256) <= 135

__device__ __forceinline__ u16 f2bf(float f) {
  unsigned u = __float_as_uint(f);
  u += 0x7FFFu + ((u >> 16) & 1u);   // RNE
  return (u16)(u >> 16);
}
__device__ __forceinline__ float bf2f(u16 b) {
  return __uint_as_float(((unsigned)b) << 16);
}

typedef const __attribute__((address_space(1))) unsigned int* gas1_t;
typedef __attribute__((address_space(3))) unsigned int* las3_t;
__device__ __forceinline__ void gload16(const u16* g, u16* l) {
  __builtin_amdgcn_global_load_lds((gas1_t)(const void*)g, (las3_t)(void*)l, 16, 0, 0);
}

// ---------------- router: logits, softmax, top2; per-block hist/gate --------
__global__ __launch_bounds__(256) void router_kernel(
    const float* __restrict__ x, const float* __restrict__ Wr,
    const float* __restrict__ br, int* __restrict__ top2e,
    float* __restrict__ top2v, int* __restrict__ histBase,
    float* __restrict__ gatePart) {
  __shared__ __align__(16) float sWr[DDIM * ENUM];   // word = d*8+e
  __shared__ __align__(16) float sX[4][DDIM];
  __shared__ int sHist[ENUM];
  __shared__ float sGate[ENUM];
  int tid = threadIdx.x;
  for (int i = tid; i < DDIM * ENUM; i += 256) sWr[i] = Wr[i];
  if (tid < ENUM) { sHist[tid] = 0; sGate[tid] = 0.f; }
  __syncthreads();
  int wave = tid >> 6, lane = tid & 63;
  int e = lane >> 3, dg = lane & 7;
  float bre = br[e];
  for (int it = 0; it < 4; ++it) {
    int t = blockIdx.x * 16 + wave * 4 + it;
    const float4* xr = (const float4*)(x + (size_t)t * DDIM);
    float4* sx4 = (float4*)sX[wave];
    sx4[lane] = xr[lane];
    sx4[lane + 64] = xr[lane + 64];
    asm volatile("s_waitcnt lgkmcnt(0)" ::: "memory");
    float acc = 0.f;
#pragma unroll 16
    for (int i = 0; i < 64; ++i) {
      float xv = sX[wave][i * 8 + dg];
      acc += xv * sWr[(i * 8 + dg) * 8 + e];
    }
    acc += __shfl_xor(acc, 1);
    acc += __shfl_xor(acc, 2);
    acc += __shfl_xor(acc, 4);
    float logit = acc + bre;
    float m = logit;
    m = fmaxf(m, __shfl_xor(m, 8));
    m = fmaxf(m, __shfl_xor(m, 16));
    m = fmaxf(m, __shfl_xor(m, 32));
    float pv = expf(logit - m);
    float s = pv;
    s += __shfl_xor(s, 8);
    s += __shfl_xor(s, 16);
    s += __shfl_xor(s, 32);
    float gate = pv / s;
    float v1 = gate; int i1 = e;
#pragma unroll
    for (int msk = 8; msk <= 32; msk <<= 1) {
      float ov = __shfl_xor(v1, msk);
      int oi = __shfl_xor(i1, msk);
      if (ov > v1 || (ov == v1 && oi < i1)) { v1 = ov; i1 = oi; }
    }
    float g2 = (e == i1) ? -1.f : gate;
    float v2 = g2; int i2 = e;
#pragma unroll
    for (int msk = 8; msk <= 32; msk <<= 1) {
      float ov = __shfl_xor(v2, msk);
      int oi = __shfl_xor(i2, msk);
      if (ov > v2 || (ov == v2 && oi < i2)) { v2 = ov; i2 = oi; }
    }
    if (lane == 0) {
      top2e[2 * t] = i1; top2e[2 * t + 1] = i2;
      top2v[2 * t] = v1; top2v[2 * t + 1] = v2;
      atomicAdd(&sHist[i1], 1);
      atomicAdd(&sHist[i2], 1);
    }
    if (dg == 0) atomicAdd(&sGate[e], gate);
  }
  __syncthreads();
  if (tid < ENUM) {
    histBase[blockIdx.x * 8 + tid] = sHist[tid];
    gatePart[blockIdx.x * 8 + tid] = sGate[tid];
  }
}

// ---------------- scan: bases, offsets, 256-tile table, aux -----------------
__global__ __launch_bounds__(256) void scan_kernel(
    int* __restrict__ histBase, const float* __restrict__ gatePart,
    int* __restrict__ offsets, int* __restrict__ counts,
    int* __restrict__ tileE, int* __restrict__ tileM, int* __restrict__ nTiles,
    float* __restrict__ auxOut) {
  __shared__ int sTot[ENUM];
  __shared__ float sG[ENUM];
  int tid = threadIdx.x, wave = tid >> 6, lane = tid & 63;
  if (tid < ENUM) sG[tid] = 0.f;
  __syncthreads();
  float loc[8] = {0, 0, 0, 0, 0, 0, 0, 0};
  for (int r = tid; r < NBLK; r += 256) {
#pragma unroll
    for (int e = 0; e < 8; ++e) loc[e] += gatePart[r * 8 + e];
  }
#pragma unroll
  for (int e = 0; e < 8; ++e) atomicAdd(&sG[e], loc[e]);
#pragma unroll
  for (int ei = 0; ei < 2; ++ei) {
    int e = wave * 2 + ei;
    int running = 0;
    for (int itb = 0; itb < NBLK / 64; ++itb) {
      int idx = (itb * 64 + lane) * 8 + e;
      int v = histBase[idx];
      int inc = v;
#pragma unroll
      for (int d = 1; d < 64; d <<= 1) {
        int o = __shfl_up(inc, d);
        if (lane >= d) inc += o;
      }
      histBase[idx] = running + inc - v;
      running += __shfl(inc, 63);
    }
    if (lane == 0) sTot[e] = running;
  }
  __syncthreads();
  if (tid == 0) {
    int off = 0, nt = 0;
#pragma unroll
    for (int e = 0; e < 8; ++e) {
      int c = sTot[e];
      offsets[e] = off; counts[e] = c; off += c;
      int mt = (c + 255) >> 8;
      for (int m = 0; m < mt; ++m) { tileE[nt] = e; tileM[nt] = m; ++nt; }
    }
    *nTiles = nt;
    float aux = 0.f;
#pragma unroll
    for (int e = 0; e < 8; ++e) {
      float pr = sG[e] / (float)NTOK;
      aux += pr * logf(pr + 1e-9f);
    }
    *auxOut = aux;
  }
}

// ---------------- place: deterministic ranks + gathered bf16 X + tokA -------
__global__ __launch_bounds__(256) void place_kernel(
    const float* __restrict__ x, const int* __restrict__ top2e,
    const float* __restrict__ top2v, const int* __restrict__ histBase,
    const int* __restrict__ offsets, int* __restrict__ tokA,
    float* __restrict__ assignW, u16* __restrict__ Xg) {
  __shared__ int sA[32];
  int tid = threadIdx.x, wave = tid >> 6, lane = tid & 63;
  int blk = blockIdx.x;
  if (tid < 32) {
    int slot = tid;
    int t = blk * 16 + (slot >> 1);
    int e = top2e[2 * t + (slot & 1)];
    float v = top2v[2 * t + (slot & 1)];
    int rank = 0;
#pragma unroll
    for (int ee = 0; ee < 8; ++ee) {
      unsigned long long mm = __ballot(e == ee);
      if (e == ee) rank = __popcll(mm & ((1ull << slot) - 1));
    }
    int a = offsets[e] + histBase[blk * 8 + e] + rank;
    sA[slot] = a;
    tokA[2 * t + (slot & 1)] = a;
    assignW[a] = v;
  }
  __syncthreads();
  for (int it = 0; it < 4; ++it) {
    int lt = wave * 4 + it;
    int t = blk * 16 + lt;
    const float4* xr = (const float4*)(x + (size_t)t * DDIM);
    float4 v0 = xr[lane * 2], v1 = xr[lane * 2 + 1];
    u16x8 o;
    o[0] = f2bf(v0.x); o[1] = f2bf(v0.y); o[2] = f2bf(v0.z); o[3] = f2bf(v0.w);
    o[4] = f2bf(v1.x); o[5] = f2bf(v1.y); o[6] = f2bf(v1.z); o[7] = f2bf(v1.w);
    int a1 = sA[2 * lt], a2 = sA[2 * lt + 1];
    *(u16x8*)(Xg + (size_t)a1 * DDIM + lane * 8) = o;
    *(u16x8*)(Xg + (size_t)a2 * DDIM + lane * 8) = o;
  }
}

// ---------------- weight transpose+convert: [K][N] f32 -> [N][K] bf16 -------
__global__ __launch_bounds__(256) void transpose_kernel(
    const float* __restrict__ W, u16* __restrict__ WT, int K, int N) {
  __shared__ float tile[64][65];
  int e = blockIdx.y;
  int tn_count = N >> 6;
  int tk = blockIdx.x / tn_count;
  int tn = blockIdx.x - tk * tn_count;
  const float* Wp = W + (size_t)e * K * N;
  u16* WTp = WT + (size_t)e * N * K;
  int c = threadIdx.x & 63, r = threadIdx.x >> 6;
#pragma unroll
  for (int i = 0; i < 16; ++i) {
    int row = r + i * 4;
    tile[row][c] = Wp[(size_t)(tk * 64 + row) * N + tn * 64 + c];
  }
  __syncthreads();
#pragma unroll
  for (int i = 0; i < 16; ++i) {
    int row = r + i * 4;
    WTp[(size_t)(tn * 64 + row) * K + tk * 64 + c] = f2bf(tile[c][row]);
  }
}

// ========== 256x256 8-phase mainloop (T2+T3+T4+T5, k-split halves) ==========
// LDS (dynamic, 128KB bytes): op(A=0/B=1)*65536 + buf*32768 + kh*16384
//   + row*64 + chunk*16, chunk swizzled by ((row>>1)&3) on both sides.
// 8 waves (2M x 4N); per-wave out 128x64; phase=(m-half, k-step), 16 MFMA.
// Stage 1 half (2 gload_lds/thread) per phase; vmcnt(8) gate at odd phases.

#define STG(SP0, SP1, SOP, SBUF, SKH, SKT)                                     \
  do {                                                                         \
    const size_t go_ = (size_t)(SKT) * 64 + (SKH) * 32;                        \
    gload16((SP0) + go_, (u16*)(ldsB + (SOP) * 65536 + (SBUF) * 32768 +        \
                                (SKH) * 16384 + w1024));                       \
    gload16((SP1) + go_, (u16*)(ldsB + (SOP) * 65536 + (SBUF) * 32768 +        \
                                (SKH) * 16384 + 8192 + w1024));                \
  } while (0)

#define PH(MH, KS, CBUF, SP0, SP1, SOP, SBUF, SKH, SKT, GATE)                  \
  do {                                                                         \
    short8 areg[4];                                                            \
    _Pragma("unroll")                                                          \
    for (int m_ = 0; m_ < 4; ++m_)                                             \
      areg[m_] = *(const short8*)(ldsB + (CBUF) * 32768 + (KS) * 16384 +       \
                                  (MH) * 4096 + m_ * 1024 + frA);              \
    if ((MH) == 0) {                                                           \
      _Pragma("unroll")                                                        \
      for (int n_ = 0; n_ < 4; ++n_)                                           \
        breg[n_] = *(const short8*)(ldsB + 65536 + (CBUF) * 32768 +            \
                                    (KS) * 16384 + n_ * 1024 + frB);           \
    }                                                                          \
    STG(SP0, SP1, SOP, SBUF, SKH, SKT);                                        \
    if (GATE) asm volatile("s_waitcnt vmcnt(8)" ::: "memory");                 \
    __builtin_amdgcn_s_barrier();                                              \
    __builtin_amdgcn_sched_barrier(0);                                         \
    __builtin_amdgcn_s_setprio(1);                                             \
    _Pragma("unroll")                                                          \
    for (int m_ = 0; m_ < 4; ++m_)                                             \
      _Pragma("unroll")                                                        \
      for (int n_ = 0; n_ < 4; ++n_)                                           \
        acc[(MH) * 4 + m_][n_] = __builtin_amdgcn_mfma_f32_16x16x32_bf16(      \
            areg[m_], breg[n_], acc[(MH) * 4 + m_][n_], 0, 0, 0);              \
    __builtin_amdgcn_s_setprio(0);                                             \
    __builtin_amdgcn_s_barrier();                                              \
    __builtin_amdgcn_sched_barrier(0);                                         \
  } while (0)

template <int K>
__device__ __forceinline__ void mainloop8(const u16* __restrict__ A,
                                          const u16* __restrict__ B,
                                          char* ldsB, f32x4 (&acc)[8][4]) {
  const int tid = threadIdx.x;
  const int lane = tid & 63, wave = tid >> 6;
  const int wr = wave >> 2, wc = wave & 3;
  const int fr = lane & 15;
  const int swzRd = (((lane >> 4) ^ ((lane >> 1) & 3)) & 3) * 16;
  const int frA = (wr * 128 + fr) * 64 + swzRd;
  const int frB = (wc * 64 + fr) * 64 + swzRd;
  const int w1024 = wave * 1024;
  // staging: thread covers row_j = j*128 + wave*16 + (lane>>2), chunk lane&3
  const int rowS = wave * 16 + (lane >> 2);
  const int cswz = ((lane & 3) ^ ((lane >> 3) & 3)) * 8;   // elements
  const u16* bA0 = A + (size_t)rowS * K + cswz;
  const u16* bA1 = A + (size_t)(rowS + 128) * K + cswz;
  const u16* bB0 = B + (size_t)rowS * K + cswz;
  const u16* bB1 = B + (size_t)(rowS + 128) * K + cswz;
  const int KT = K / 64, NIT = KT / 2;
  short8 breg[4];

  // prologue (FIFO): T0.Ak0, T0.Bk0, T0.Ak1, T0.Bk1, T1.Ak0, T1.Bk0
  STG(bA0, bA1, 0, 0, 0, 0);
  STG(bB0, bB1, 1, 0, 0, 0);
  STG(bA0, bA1, 0, 0, 1, 0);
  STG(bB0, bB1, 1, 0, 1, 0);
  STG(bA0, bA1, 0, 1, 0, 1);
  STG(bB0, bB1, 1, 1, 0, 1);
  asm volatile("s_waitcnt vmcnt(8)" ::: "memory");
  __builtin_amdgcn_s_barrier();
  __builtin_amdgcn_sched_barrier(0);

#pragma unroll 1
  for (int it = 0; it < NIT; ++it) {
    const int t1 = 2 * it + 1;
    const int t2 = (2 * it + 2) & (KT - 1);   // wrapped tail stages keep
    const int t3 = (2 * it + 3) & (KT - 1);   // vmcnt counts exact
    PH(0, 0, 0, bA0, bA1, 0, 1, 1, t1, 0);    // stage T(t+1).A.k1 -> buf1
    PH(1, 0, 0, bB0, bB1, 1, 1, 1, t1, 1);    // stage T(t+1).B.k1, GATE
    PH(0, 1, 0, bA0, bA1, 0, 0, 0, t2, 0);    // stage T(t+2).A.k0 -> buf0
    PH(1, 1, 0, bB0, bB1, 1, 0, 0, t2, 1);    // GATE
    PH(0, 0, 1, bA0, bA1, 0, 0, 1, t2, 0);    // stage T(t+2).A.k1 -> buf0
    PH(1, 0, 1, bB0, bB1, 1, 0, 1, t2, 1);    // GATE
    PH(0, 1, 1, bA0, bA1, 0, 1, 0, t3, 0);    // stage T(t+3).A.k0 -> buf1
    PH(1, 1, 1, bB0, bB1, 1, 1, 0, t3, 1);    // GATE
  }
}

// ---------------- GEMM1: h = relu(Xg @ W1 + b1), bf16 out -------------------
__global__ __launch_bounds__(512, 1) void gemm1_kernel(
    const u16* __restrict__ Xg, const u16* __restrict__ W1T,
    const float* __restrict__ b1, u16* __restrict__ h,
    const int* __restrict__ counts, const int* __restrict__ offsets,
    const int* __restrict__ tileE, const int* __restrict__ tileM,
    const int* __restrict__ nTiles) {
  extern __shared__ char ldsB[];
  if ((int)blockIdx.x >= *nTiles) return;
  int e = tileE[blockIdx.x], mtile = tileM[blockIdx.x];
  int ntile = blockIdx.y;
  int cnt = counts[e], off = offsets[e];
  const u16* A = Xg + (size_t)(off + mtile * 256) * DDIM;
  const u16* B = W1T + ((size_t)e * FDIM + ntile * 256) * DDIM;
  f32x4 acc[8][4] = {};
  mainloop8<DDIM>(A, B, ldsB, acc);
  int lane = threadIdx.x & 63, wave = threadIdx.x >> 6;
  int wr = wave >> 2, wc = wave & 3;
  int cl = lane & 15, rq = (lane >> 4) * 4;
#pragma unroll
  for (int ai = 0; ai < 8; ++ai) {
#pragma unroll
    for (int i = 0; i < 4; ++i) {
      int gr = mtile * 256 + wr * 128 + ai * 16 + rq + i;
      if (gr < cnt) {
#pragma unroll
        for (int n = 0; n < 4; ++n) {
          int gc = ntile * 256 + wc * 64 + n * 16 + cl;
          float v = acc[ai][n][i] + b1[e * FDIM + gc];
          v = fmaxf(v, 0.f);
          h[(size_t)(off + gr) * FDIM + gc] = f2bf(v);
        }
      }
    }
  }
}

// ---------------- GEMM2: z[a] = w_a * (h @ W2 + b2), bf16 -------------------
__global__ __launch_bounds__(512, 1) void gemm2_kernel(
    const u16* __restrict__ h, const u16* __restrict__ W2T,
    const float* __restrict__ b2, const float* __restrict__ assignW,
    const int* __restrict__ counts, const int* __restrict__ offsets,
    const int* __restrict__ tileE, const int* __restrict__ tileM,
    const int* __restrict__ nTiles, u16* __restrict__ z) {
  extern __shared__ char ldsB[];
  if ((int)blockIdx.x >= *nTiles) return;
  int e = tileE[blockIdx.x], mtile = tileM[blockIdx.x];
  int ntile = blockIdx.y;
  int cnt = counts[e], off = offsets[e];
  const u16* A = h + (size_t)(off + mtile * 256) * FDIM;
  const u16* B = W2T + ((size_t)e * DDIM + ntile * 256) * FDIM;
  f32x4 acc[8][4] = {};
  mainloop8<FDIM>(A, B, ldsB, acc);
  int lane = threadIdx.x & 63, wave = threadIdx.x >> 6;
  int wr = wave >> 2, wc = wave & 3;
  int cl = lane & 15, rq = (lane >> 4) * 4;
#pragma unroll
  for (int ai = 0; ai < 8; ++ai) {
#pragma unroll
    for (int i = 0; i < 4; ++i) {
      int gr = mtile * 256 + wr * 128 + ai * 16 + rq + i;
      if (gr < cnt) {
        int a = off + gr;
        float w = assignW[a];
#pragma unroll
        for (int n = 0; n < 4; ++n) {
          int gc = ntile * 256 + wc * 64 + n * 16 + cl;
          float v = (acc[ai][n][i] + b2[e * DDIM + gc]) * w;
          z[(size_t)a * DDIM + gc] = f2bf(v);
        }
      }
    }
  }
}

// ---------------- combine: out[t] = z[a1(t)] + z[a2(t)] ---------------------
__global__ __launch_bounds__(256) void combine_kernel(
    const u16* __restrict__ z, const int* __restrict__ tokA,
    float* __restrict__ out) {
  int tid = threadIdx.x, wave = tid >> 6, lane = tid & 63;
  int t = blockIdx.x * 4 + wave;
  int a1 = tokA[2 * t], a2 = tokA[2 * t + 1];
  u16x8 v1 = *(const u16x8*)(z + (size_t)a1 * DDIM + lane * 8);
  u16x8 v2 = *(const u16x8*)(z + (size_t)a2 * DDIM + lane * 8);
  float4 o0, o1;
  o0.x = bf2f(v1[0]) + bf2f(v2[0]);
  o0.y = bf2f(v1[1]) + bf2f(v2[1]);
  o0.z = bf2f(v1[2]) + bf2f(v2[2]);
  o0.w = bf2f(v1[3]) + bf2f(v2[3]);
  o1.x = bf2f(v1[4]) + bf2f(v2[4]);
  o1.y = bf2f(v1[5]) + bf2f(v2[5]);
  o1.z = bf2f(v1[6]) + bf2f(v2[6]);
  o1.w = bf2f(v1[7]) + bf2f(v2[7]);
  float4* o = (float4*)(out + (size_t)t * DDIM + lane * 8);
  o[0] = o0;
  o[1] = o1;
}

extern "C" void kernel_launch(void* const* d_in, const int* in_sizes, int n_in,
                              void* d_out, int out_size, void* d_ws, size_t ws_size,
                              hipStream_t stream) {
  const float* x  = (const float*)d_in[0];
  const float* Wr = (const float*)d_in[1];
  const float* br = (const float*)d_in[2];
  const float* W1 = (const float*)d_in[3];
  const float* b1 = (const float*)d_in[4];
  const float* W2 = (const float*)d_in[5];
  const float* b2 = (const float*)d_in[6];
  float* out = (float*)d_out;

  char* ws = (char*)d_ws;
  size_t p = 0;
  auto alloc = [&](size_t bytes) -> void* {
    void* r = ws + p;
    p = (p + bytes + 255) & ~(size_t)255;
    return r;
  };
  int* counts     = (int*)alloc(ENUM * 4);
  int* offsets    = (int*)alloc(ENUM * 4);
  int* nTiles     = (int*)alloc(4);
  int* tileE      = (int*)alloc(MAXT * 4);
  int* tileM      = (int*)alloc(MAXT * 4);
  int* top2e      = (int*)alloc((size_t)NTOK * 2 * 4);
  float* top2v    = (float*)alloc((size_t)NTOK * 2 * 4);
  int* tokA       = (int*)alloc((size_t)NTOK * 2 * 4);
  float* assignW  = (float*)alloc((size_t)APAD * 4);
  int* histBase   = (int*)alloc((size_t)NBLK * 8 * 4);
  float* gatePart = (float*)alloc((size_t)NBLK * 8 * 4);
  u16* W1T        = (u16*)alloc((size_t)ENUM * FDIM * DDIM * 2);
  u16* W2T        = (u16*)alloc((size_t)ENUM * DDIM * FDIM * 2);
  u16* Xg         = (u16*)alloc((size_t)APAD * DDIM * 2);
  u16* hbuf       = (u16*)alloc((size_t)APAD * FDIM * 2);
  u16* z          = Xg;   // alias: Xg dead after gemm1
  (void)in_sizes; (void)n_in; (void)out_size; (void)ws_size;  // ~203 MB used

  // allow 128KB dynamic LDS (no-op if already permitted)
  (void)hipFuncSetAttribute((const void*)gemm1_kernel,
                            hipFuncAttributeMaxDynamicSharedMemorySize, 131072);
  (void)hipFuncSetAttribute((const void*)gemm2_kernel,
                            hipFuncAttributeMaxDynamicSharedMemorySize, 131072);

  transpose_kernel<<<dim3(256, 8), 256, 0, stream>>>(W1, W1T, DDIM, FDIM);
  transpose_kernel<<<dim3(256, 8), 256, 0, stream>>>(W2, W2T, FDIM, DDIM);
  router_kernel<<<NBLK, 256, 0, stream>>>(x, Wr, br, top2e, top2v, histBase,
                                          gatePart);
  scan_kernel<<<1, 256, 0, stream>>>(histBase, gatePart, offsets, counts,
                                     tileE, tileM, nTiles,
                                     out + (size_t)NTOK * DDIM);
  place_kernel<<<NBLK, 256, 0, stream>>>(x, top2e, top2v, histBase, offsets,
                                         tokA, assignW, Xg);
  gemm1_kernel<<<dim3(MAXT, 8), 512, 131072, stream>>>(
      Xg, W1T, b1, hbuf, counts, offsets, tileE, tileM, nTiles);
  gemm2_kernel<<<dim3(MAXT, 2), 512, 131072, stream>>>(
      hbuf, W2T, b2, assignW, counts, offsets, tileE, tileM, nTiles, z);
  combine_kernel<<<NTOK / 4, 256, 0, stream>>>(z, tokA, out);
}

// Round 5
// 317.328 us; speedup vs baseline: 3.7441x; 1.0329x over previous
//
#include <hip/hip_runtime.h>
#include <math.h>

typedef unsigned short u16;
typedef __attribute__((ext_vector_type(8))) short short8;
typedef __attribute__((ext_vector_type(8))) u16 u16x8;
typedef __attribute__((ext_vector_type(4))) float f32x4;

#define NTOK 16384   // B*S
#define DDIM 512
#define FDIM 2048
#define ENUM 8
#define NBLK 1024    // router/place blocks (16 tokens each)
#define APAD (32768 + 256)
#define NT1CAP 136   // sum ceil(cnt_e/256) <= 135
#define NT2CAP 264   // sum ceil(cnt_e/128) <= 263
#define G1GRID 1088  // 8 * 136
#define G2GRID 528   // 8 * 66

__device__ __forceinline__ u16 f2bf(float f) {
  unsigned u = __float_as_uint(f);
  u += 0x7FFFu + ((u >> 16) & 1u);   // RNE
  return (u16)(u >> 16);
}
__device__ __forceinline__ float bf2f(u16 b) {
  return __uint_as_float(((unsigned)b) << 16);
}

typedef const __attribute__((address_space(1))) unsigned int* gas1_t;
typedef __attribute__((address_space(3))) unsigned int* las3_t;
__device__ __forceinline__ void gload16(const u16* g, u16* l) {
  __builtin_amdgcn_global_load_lds((gas1_t)(const void*)g, (las3_t)(void*)l, 16, 0, 0);
}

// ---------------- router: logits, softmax, top2; per-block hist/gate --------
__global__ __launch_bounds__(256) void router_kernel(
    const float* __restrict__ x, const float* __restrict__ Wr,
    const float* __restrict__ br, int* __restrict__ top2e,
    float* __restrict__ top2v, int* __restrict__ histBase,
    float* __restrict__ gatePart) {
  __shared__ __align__(16) float sWr[DDIM * ENUM];   // word = d*8+e
  __shared__ __align__(16) float sX[4][DDIM];
  __shared__ int sHist[ENUM];
  __shared__ float sGate[ENUM];
  int tid = threadIdx.x;
  for (int i = tid; i < DDIM * ENUM; i += 256) sWr[i] = Wr[i];
  if (tid < ENUM) { sHist[tid] = 0; sGate[tid] = 0.f; }
  __syncthreads();
  int wave = tid >> 6, lane = tid & 63;
  int e = lane >> 3, dg = lane & 7;
  float bre = br[e];
  for (int it = 0; it < 4; ++it) {
    int t = blockIdx.x * 16 + wave * 4 + it;
    const float4* xr = (const float4*)(x + (size_t)t * DDIM);
    float4* sx4 = (float4*)sX[wave];
    sx4[lane] = xr[lane];
    sx4[lane + 64] = xr[lane + 64];
    asm volatile("s_waitcnt lgkmcnt(0)" ::: "memory");
    float acc = 0.f;
#pragma unroll 16
    for (int i = 0; i < 64; ++i) {
      float xv = sX[wave][i * 8 + dg];
      acc += xv * sWr[(i * 8 + dg) * 8 + e];
    }
    acc += __shfl_xor(acc, 1);
    acc += __shfl_xor(acc, 2);
    acc += __shfl_xor(acc, 4);
    float logit = acc + bre;
    float m = logit;
    m = fmaxf(m, __shfl_xor(m, 8));
    m = fmaxf(m, __shfl_xor(m, 16));
    m = fmaxf(m, __shfl_xor(m, 32));
    float pv = expf(logit - m);
    float s = pv;
    s += __shfl_xor(s, 8);
    s += __shfl_xor(s, 16);
    s += __shfl_xor(s, 32);
    float gate = pv / s;
    float v1 = gate; int i1 = e;
#pragma unroll
    for (int msk = 8; msk <= 32; msk <<= 1) {
      float ov = __shfl_xor(v1, msk);
      int oi = __shfl_xor(i1, msk);
      if (ov > v1 || (ov == v1 && oi < i1)) { v1 = ov; i1 = oi; }
    }
    float g2 = (e == i1) ? -1.f : gate;
    float v2 = g2; int i2 = e;
#pragma unroll
    for (int msk = 8; msk <= 32; msk <<= 1) {
      float ov = __shfl_xor(v2, msk);
      int oi = __shfl_xor(i2, msk);
      if (ov > v2 || (ov == v2 && oi < i2)) { v2 = ov; i2 = oi; }
    }
    if (lane == 0) {
      top2e[2 * t] = i1; top2e[2 * t + 1] = i2;
      top2v[2 * t] = v1; top2v[2 * t + 1] = v2;
      atomicAdd(&sHist[i1], 1);
      atomicAdd(&sHist[i2], 1);
    }
    if (dg == 0) atomicAdd(&sGate[e], gate);
  }
  __syncthreads();
  if (tid < ENUM) {
    histBase[blockIdx.x * 8 + tid] = sHist[tid];
    gatePart[blockIdx.x * 8 + tid] = sGate[tid];
  }
}

// ---------------- scan: bases, offsets, tile tables (256 & 128), aux --------
__global__ __launch_bounds__(256) void scan_kernel(
    int* __restrict__ histBase, const float* __restrict__ gatePart,
    int* __restrict__ offsets, int* __restrict__ counts,
    int* __restrict__ tileE1, int* __restrict__ tileM1,
    int* __restrict__ tileE2, int* __restrict__ tileM2,
    int* __restrict__ nT, float* __restrict__ auxOut) {
  __shared__ int sTot[ENUM];
  __shared__ float sG[ENUM];
  int tid = threadIdx.x, wave = tid >> 6, lane = tid & 63;
  if (tid < ENUM) sG[tid] = 0.f;
  __syncthreads();
  float loc[8] = {0, 0, 0, 0, 0, 0, 0, 0};
  for (int r = tid; r < NBLK; r += 256) {
#pragma unroll
    for (int e = 0; e < 8; ++e) loc[e] += gatePart[r * 8 + e];
  }
#pragma unroll
  for (int e = 0; e < 8; ++e) atomicAdd(&sG[e], loc[e]);
#pragma unroll
  for (int ei = 0; ei < 2; ++ei) {
    int e = wave * 2 + ei;
    int running = 0;
    for (int itb = 0; itb < NBLK / 64; ++itb) {
      int idx = (itb * 64 + lane) * 8 + e;
      int v = histBase[idx];
      int inc = v;
#pragma unroll
      for (int d = 1; d < 64; d <<= 1) {
        int o = __shfl_up(inc, d);
        if (lane >= d) inc += o;
      }
      histBase[idx] = running + inc - v;
      running += __shfl(inc, 63);
    }
    if (lane == 0) sTot[e] = running;
  }
  __syncthreads();
  if (tid == 0) {
    int off = 0, nt1 = 0, nt2 = 0;
#pragma unroll
    for (int e = 0; e < 8; ++e) {
      int c = sTot[e];
      offsets[e] = off; counts[e] = c; off += c;
      int mt1 = (c + 255) >> 8;
      for (int m = 0; m < mt1; ++m) { tileE1[nt1] = e; tileM1[nt1] = m; ++nt1; }
      int mt2 = (c + 127) >> 7;
      for (int m = 0; m < mt2; ++m) { tileE2[nt2] = e; tileM2[nt2] = m; ++nt2; }
    }
    nT[0] = nt1; nT[1] = nt2;
    float aux = 0.f;
#pragma unroll
    for (int e = 0; e < 8; ++e) {
      float pr = sG[e] / (float)NTOK;
      aux += pr * logf(pr + 1e-9f);
    }
    *auxOut = aux;
  }
}

// ---------------- place: deterministic ranks + gathered bf16 X + tokA -------
__global__ __launch_bounds__(256) void place_kernel(
    const float* __restrict__ x, const int* __restrict__ top2e,
    const float* __restrict__ top2v, const int* __restrict__ histBase,
    const int* __restrict__ offsets, int* __restrict__ tokA,
    float* __restrict__ assignW, u16* __restrict__ Xg) {
  __shared__ int sA[32];
  int tid = threadIdx.x, wave = tid >> 6, lane = tid & 63;
  int blk = blockIdx.x;
  if (tid < 32) {
    int slot = tid;
    int t = blk * 16 + (slot >> 1);
    int e = top2e[2 * t + (slot & 1)];
    float v = top2v[2 * t + (slot & 1)];
    int rank = 0;
#pragma unroll
    for (int ee = 0; ee < 8; ++ee) {
      unsigned long long mm = __ballot(e == ee);
      if (e == ee) rank = __popcll(mm & ((1ull << slot) - 1));
    }
    int a = offsets[e] + histBase[blk * 8 + e] + rank;
    sA[slot] = a;
    tokA[2 * t + (slot & 1)] = a;
    assignW[a] = v;
  }
  __syncthreads();
  for (int it = 0; it < 4; ++it) {
    int lt = wave * 4 + it;
    int t = blk * 16 + lt;
    const float4* xr = (const float4*)(x + (size_t)t * DDIM);
    float4 v0 = xr[lane * 2], v1 = xr[lane * 2 + 1];
    u16x8 o;
    o[0] = f2bf(v0.x); o[1] = f2bf(v0.y); o[2] = f2bf(v0.z); o[3] = f2bf(v0.w);
    o[4] = f2bf(v1.x); o[5] = f2bf(v1.y); o[6] = f2bf(v1.z); o[7] = f2bf(v1.w);
    int a1 = sA[2 * lt], a2 = sA[2 * lt + 1];
    *(u16x8*)(Xg + (size_t)a1 * DDIM + lane * 8) = o;
    *(u16x8*)(Xg + (size_t)a2 * DDIM + lane * 8) = o;
  }
}

// -------- fused weight transpose+convert: W1 and W2, vectorized stores ------
__global__ __launch_bounds__(256) void transpose_kernel(
    const float* __restrict__ W1, const float* __restrict__ W2,
    u16* __restrict__ W1T, u16* __restrict__ W2T) {
  __shared__ float tile[64][65];
  int q = threadIdx.x;
  int half = blockIdx.y >> 3, e = blockIdx.y & 7;
  const float* W = half ? W2 : W1;
  u16* WT = half ? W2T : W1T;
  int K = half ? FDIM : DDIM, N = half ? DDIM : FDIM;
  int tnc = N >> 6;
  int tk = blockIdx.x / tnc, tn = blockIdx.x - tk * tnc;
  const float* Wp = W + (size_t)e * K * N + (size_t)(tk * 64) * N + tn * 64;
#pragma unroll
  for (int i = 0; i < 4; ++i) {
    int row = (q >> 4) + i * 16, c4 = (q & 15) * 4;
    float4 v = *(const float4*)(Wp + (size_t)row * N + c4);
    tile[row][c4] = v.x; tile[row][c4 + 1] = v.y;
    tile[row][c4 + 2] = v.z; tile[row][c4 + 3] = v.w;
  }
  __syncthreads();
  u16* WTp = WT + (size_t)e * N * K + (size_t)(tn * 64) * K + tk * 64;
#pragma unroll
  for (int p = 0; p < 2; ++p) {
    int n = (q >> 3) + p * 32, k0 = (q & 7) * 8;
    u16x8 o;
#pragma unroll
    for (int j = 0; j < 8; ++j) o[j] = f2bf(tile[k0 + j][n]);
    *(u16x8*)(WTp + (size_t)n * K + k0) = o;
  }
}

// ========== GEMM1: 256x256 8-phase mainloop (unchanged structure) ===========
#define STG(SP0, SP1, SOP, SBUF, SKH, SKT)                                     \
  do {                                                                         \
    const size_t go_ = (size_t)(SKT) * 64 + (SKH) * 32;                        \
    gload16((SP0) + go_, (u16*)(ldsB + (SOP) * 65536 + (SBUF) * 32768 +        \
                                (SKH) * 16384 + w1024));                       \
    gload16((SP1) + go_, (u16*)(ldsB + (SOP) * 65536 + (SBUF) * 32768 +        \
                                (SKH) * 16384 + 8192 + w1024));                \
  } while (0)

#define PH(MH, KS, CBUF, SP0, SP1, SOP, SBUF, SKH, SKT, GATE)                  \
  do {                                                                         \
    short8 areg[4];                                                            \
    _Pragma("unroll")                                                          \
    for (int m_ = 0; m_ < 4; ++m_)                                             \
      areg[m_] = *(const short8*)(ldsB + (CBUF) * 32768 + (KS) * 16384 +       \
                                  (MH) * 4096 + m_ * 1024 + frA);              \
    if ((MH) == 0) {                                                           \
      _Pragma("unroll")                                                        \
      for (int n_ = 0; n_ < 4; ++n_)                                           \
        breg[n_] = *(const short8*)(ldsB + 65536 + (CBUF) * 32768 +            \
                                    (KS) * 16384 + n_ * 1024 + frB);           \
    }                                                                          \
    STG(SP0, SP1, SOP, SBUF, SKH, SKT);                                        \
    if (GATE) asm volatile("s_waitcnt vmcnt(8)" ::: "memory");                 \
    __builtin_amdgcn_s_barrier();                                              \
    __builtin_amdgcn_sched_barrier(0);                                         \
    __builtin_amdgcn_s_setprio(1);                                             \
    _Pragma("unroll")                                                          \
    for (int m_ = 0; m_ < 4; ++m_)                                             \
      _Pragma("unroll")                                                        \
      for (int n_ = 0; n_ < 4; ++n_)                                           \
        acc[(MH) * 4 + m_][n_] = __builtin_amdgcn_mfma_f32_16x16x32_bf16(      \
            areg[m_], breg[n_], acc[(MH) * 4 + m_][n_], 0, 0, 0);              \
    __builtin_amdgcn_s_setprio(0);                                             \
    __builtin_amdgcn_s_barrier();                                              \
    __builtin_amdgcn_sched_barrier(0);                                         \
  } while (0)

template <int K>
__device__ __forceinline__ void mainloop8(const u16* __restrict__ A,
                                          const u16* __restrict__ B,
                                          char* ldsB, f32x4 (&acc)[8][4]) {
  const int tid = threadIdx.x;
  const int lane = tid & 63, wave = tid >> 6;
  const int wr = wave >> 2, wc = wave & 3;
  const int fr = lane & 15;
  const int swzRd = (((lane >> 4) ^ ((lane >> 1) & 3)) & 3) * 16;
  const int frA = (wr * 128 + fr) * 64 + swzRd;
  const int frB = (wc * 64 + fr) * 64 + swzRd;
  const int w1024 = wave * 1024;
  const int rowS = wave * 16 + (lane >> 2);
  const int cswz = ((lane & 3) ^ ((lane >> 3) & 3)) * 8;   // elements
  const u16* bA0 = A + (size_t)rowS * K + cswz;
  const u16* bA1 = A + (size_t)(rowS + 128) * K + cswz;
  const u16* bB0 = B + (size_t)rowS * K + cswz;
  const u16* bB1 = B + (size_t)(rowS + 128) * K + cswz;
  const int KT = K / 64, NIT = KT / 2;
  short8 breg[4];

  STG(bA0, bA1, 0, 0, 0, 0);
  STG(bB0, bB1, 1, 0, 0, 0);
  STG(bA0, bA1, 0, 0, 1, 0);
  STG(bB0, bB1, 1, 0, 1, 0);
  STG(bA0, bA1, 0, 1, 0, 1);
  STG(bB0, bB1, 1, 1, 0, 1);
  asm volatile("s_waitcnt vmcnt(8)" ::: "memory");
  __builtin_amdgcn_s_barrier();
  __builtin_amdgcn_sched_barrier(0);

#pragma unroll 1
  for (int it = 0; it < NIT; ++it) {
    const int t1 = 2 * it + 1;
    const int t2 = (2 * it + 2) & (KT - 1);
    const int t3 = (2 * it + 3) & (KT - 1);
    PH(0, 0, 0, bA0, bA1, 0, 1, 1, t1, 0);
    PH(1, 0, 0, bB0, bB1, 1, 1, 1, t1, 1);
    PH(0, 1, 0, bA0, bA1, 0, 0, 0, t2, 0);
    PH(1, 1, 0, bB0, bB1, 1, 0, 0, t2, 1);
    PH(0, 0, 1, bA0, bA1, 0, 0, 1, t2, 0);
    PH(1, 0, 1, bB0, bB1, 1, 0, 1, t2, 1);
    PH(0, 1, 1, bA0, bA1, 0, 1, 0, t3, 0);
    PH(1, 1, 1, bB0, bB1, 1, 1, 0, t3, 1);
  }
}

__global__ __launch_bounds__(512, 1) void gemm1_kernel(
    const u16* __restrict__ Xg, const u16* __restrict__ W1T,
    const float* __restrict__ b1, u16* __restrict__ h,
    const int* __restrict__ counts, const int* __restrict__ offsets,
    const int* __restrict__ tileE1, const int* __restrict__ tileM1,
    const int* __restrict__ nT) {
  extern __shared__ char ldsB[];
  // XCD-chunked decode: same tile's 8 ntiles consecutive on one XCD
  int wg = blockIdx.x;
  int L = (wg & 7) * (G1GRID / 8) + (wg >> 3);
  int tile = L >> 3, ntile = L & 7;
  if (tile >= nT[0]) return;
  int e = tileE1[tile], mtile = tileM1[tile];
  int cnt = counts[e], off = offsets[e];
  const u16* A = Xg + (size_t)(off + mtile * 256) * DDIM;
  const u16* B = W1T + ((size_t)e * FDIM + ntile * 256) * DDIM;
  f32x4 acc[8][4] = {};
  mainloop8<DDIM>(A, B, ldsB, acc);
  int lane = threadIdx.x & 63, wave = threadIdx.x >> 6;
  int wr = wave >> 2, wc = wave & 3;
  int cl = lane & 15, rq = (lane >> 4) * 4;
#pragma unroll
  for (int ai = 0; ai < 8; ++ai) {
#pragma unroll
    for (int i = 0; i < 4; ++i) {
      int gr = mtile * 256 + wr * 128 + ai * 16 + rq + i;
      if (gr < cnt) {
#pragma unroll
        for (int n = 0; n < 4; ++n) {
          int gc = ntile * 256 + wc * 64 + n * 16 + cl;
          float v = acc[ai][n][i] + b1[e * FDIM + gc];
          v = fmaxf(v, 0.f);
          h[(size_t)(off + gr) * FDIM + gc] = f2bf(v);
        }
      }
    }
  }
}

// ========== GEMM2: 128x256 tile, 2-phase/K-step kh-split pipeline ===========
// LDS 96KB: A[buf][kh] = buf*16384 + kh*8192 (128 rows x 32k);
//           B[buf][kh] = 32768 + buf*32768 + kh*16384 (256 rows x 32k).
// 8 waves 2Mx4N, wave-tile 64x64, acc[4][4]. Per phase: 8 ds_read_b128,
// 3 gload_lds (stage one kh-half of next/next-next K-step), vmcnt(6) gate.
#define STG2(SBUF, SKH, SKT)                                                   \
  do {                                                                         \
    const size_t go_ = (size_t)(SKT) * 64 + (SKH) * 32;                        \
    gload16(a2g + go_, (u16*)(ldsB + (SBUF) * 16384 + (SKH) * 8192 + w1024));  \
    gload16(b2g0 + go_, (u16*)(ldsB + 32768 + (SBUF) * 32768 +                 \
                               (SKH) * 16384 + w1024));                        \
    gload16(b2g1 + go_, (u16*)(ldsB + 32768 + (SBUF) * 32768 +                 \
                               (SKH) * 16384 + 8192 + w1024));                 \
  } while (0)

#define PH2(KS, CBUF, SBUF, SKH, SKT)                                          \
  do {                                                                         \
    short8 areg[4], breg2[4];                                                  \
    _Pragma("unroll")                                                          \
    for (int m_ = 0; m_ < 4; ++m_)                                             \
      areg[m_] = *(const short8*)(ldsB + (CBUF) * 16384 + (KS) * 8192 +        \
                                  m_ * 1024 + frA2);                           \
    _Pragma("unroll")                                                          \
    for (int n_ = 0; n_ < 4; ++n_)                                             \
      breg2[n_] = *(const short8*)(ldsB + 32768 + (CBUF) * 32768 +             \
                                   (KS) * 16384 + n_ * 1024 + frB2);           \
    STG2(SBUF, SKH, SKT);                                                      \
    asm volatile("s_waitcnt vmcnt(6)" ::: "memory");                           \
    __builtin_amdgcn_s_barrier();                                              \
    __builtin_amdgcn_sched_barrier(0);                                         \
    __builtin_amdgcn_s_setprio(1);                                             \
    _Pragma("unroll")                                                          \
    for (int m_ = 0; m_ < 4; ++m_)                                             \
      _Pragma("unroll")                                                        \
      for (int n_ = 0; n_ < 4; ++n_)                                           \
        acc[m_][n_] = __builtin_amdgcn_mfma_f32_16x16x32_bf16(                 \
            areg[m_], breg2[n_], acc[m_][n_], 0, 0, 0);                        \
    __builtin_amdgcn_s_setprio(0);                                             \
    __builtin_amdgcn_s_barrier();                                              \
    __builtin_amdgcn_sched_barrier(0);                                         \
  } while (0)

template <int K>
__device__ __forceinline__ void mainloop2(const u16* __restrict__ A,
                                          const u16* __restrict__ B,
                                          char* ldsB, f32x4 (&acc)[4][4]) {
  const int tid = threadIdx.x;
  const int lane = tid & 63, wave = tid >> 6;
  const int wr = wave >> 2, wc = wave & 3;
  const int fr = lane & 15;
  const int slot = ((lane >> 4) ^ ((lane >> 1) & 3)) & 3;
  const int frA2 = (wr * 64 + fr) * 64 + slot * 16;
  const int frB2 = (wc * 64 + fr) * 64 + slot * 16;
  const int w1024 = wave * 1024;
  const int rowS = tid >> 2;
  const int cswz = ((tid & 3) ^ ((tid >> 3) & 3)) * 8;   // elements
  const u16* a2g = A + (size_t)rowS * K + cswz;
  const u16* b2g0 = B + (size_t)rowS * K + cswz;
  const u16* b2g1 = B + (size_t)(rowS + 128) * K + cswz;
  const int KT = K / 64;

  // prologue: T0.kh0, T0.kh1, T1.kh0 (9 loads/wave); wait oldest 3
  STG2(0, 0, 0);
  STG2(0, 1, 0);
  STG2(1, 0, 1);
  asm volatile("s_waitcnt vmcnt(6)" ::: "memory");
  __builtin_amdgcn_s_barrier();
  __builtin_amdgcn_sched_barrier(0);

#pragma unroll 1
  for (int tt = 0; tt < KT / 2; ++tt) {
    const int t0 = 2 * tt;
    const int u2 = (t0 + 2) & (KT - 1);
    const int u3 = (t0 + 3) & (KT - 1);
    PH2(0, 0, 1, 1, t0 + 1);   // step t0,  ks0; stage T(t0+1).kh1 -> buf1
    PH2(1, 0, 0, 0, u2);       // step t0,  ks1; stage T(t0+2).kh0 -> buf0
    PH2(0, 1, 0, 1, u2);       // step t0+1,ks0; stage T(t0+2).kh1 -> buf0
    PH2(1, 1, 1, 0, u3);       // step t0+1,ks1; stage T(t0+3).kh0 -> buf1
  }
}

__global__ __launch_bounds__(512, 1) void gemm2_kernel(
    const u16* __restrict__ h, const u16* __restrict__ W2T,
    const float* __restrict__ b2, const float* __restrict__ assignW,
    const int* __restrict__ counts, const int* __restrict__ offsets,
    const int* __restrict__ tileE2, const int* __restrict__ tileM2,
    const int* __restrict__ nT, u16* __restrict__ z) {
  extern __shared__ char ldsB[];
  int wg = blockIdx.x;
  int L = (wg & 7) * (G2GRID / 8) + (wg >> 3);
  int tile = L >> 1, ntile = L & 1;
  if (tile >= nT[1]) return;
  int e = tileE2[tile], mtile = tileM2[tile];
  int cnt = counts[e], off = offsets[e];
  const u16* A = h + (size_t)(off + mtile * 128) * FDIM;
  const u16* B = W2T + ((size_t)e * DDIM + ntile * 256) * FDIM;
  f32x4 acc[4][4] = {};
  mainloop2<FDIM>(A, B, ldsB, acc);
  int lane = threadIdx.x & 63, wave = threadIdx.x >> 6;
  int wr = wave >> 2, wc = wave & 3;
  int cl = lane & 15, rq = (lane >> 4) * 4;
#pragma unroll
  for (int m = 0; m < 4; ++m) {
#pragma unroll
    for (int i = 0; i < 4; ++i) {
      int gr = mtile * 128 + wr * 64 + m * 16 + rq + i;
      if (gr < cnt) {
        int a = off + gr;
        float w = assignW[a];
#pragma unroll
        for (int n = 0; n < 4; ++n) {
          int gc = ntile * 256 + wc * 64 + n * 16 + cl;
          float v = (acc[m][n][i] + b2[e * DDIM + gc]) * w;
          z[(size_t)a * DDIM + gc] = f2bf(v);
        }
      }
    }
  }
}

// ---------------- combine: out[t] = z[a1(t)] + z[a2(t)] ---------------------
__global__ __launch_bounds__(256) void combine_kernel(
    const u16* __restrict__ z, const int* __restrict__ tokA,
    float* __restrict__ out) {
  int tid = threadIdx.x, wave = tid >> 6, lane = tid & 63;
  int t = blockIdx.x * 4 + wave;
  int a1 = tokA[2 * t], a2 = tokA[2 * t + 1];
  u16x8 v1 = *(const u16x8*)(z + (size_t)a1 * DDIM + lane * 8);
  u16x8 v2 = *(const u16x8*)(z + (size_t)a2 * DDIM + lane * 8);
  float4 o0, o1;
  o0.x = bf2f(v1[0]) + bf2f(v2[0]);
  o0.y = bf2f(v1[1]) + bf2f(v2[1]);
  o0.z = bf2f(v1[2]) + bf2f(v2[2]);
  o0.w = bf2f(v1[3]) + bf2f(v2[3]);
  o1.x = bf2f(v1[4]) + bf2f(v2[4]);
  o1.y = bf2f(v1[5]) + bf2f(v2[5]);
  o1.z = bf2f(v1[6]) + bf2f(v2[6]);
  o1.w = bf2f(v1[7]) + bf2f(v2[7]);
  float4* o = (float4*)(out + (size_t)t * DDIM + lane * 8);
  o[0] = o0;
  o[1] = o1;
}

extern "C" void kernel_launch(void* const* d_in, const int* in_sizes, int n_in,
                              void* d_out, int out_size, void* d_ws, size_t ws_size,
                              hipStream_t stream) {
  const float* x  = (const float*)d_in[0];
  const float* Wr = (const float*)d_in[1];
  const float* br = (const float*)d_in[2];
  const float* W1 = (const float*)d_in[3];
  const float* b1 = (const float*)d_in[4];
  const float* W2 = (const float*)d_in[5];
  const float* b2 = (const float*)d_in[6];
  float* out = (float*)d_out;

  char* ws = (char*)d_ws;
  size_t p = 0;
  auto alloc = [&](size_t bytes) -> void* {
    void* r = ws + p;
    p = (p + bytes + 255) & ~(size_t)255;
    return r;
  };
  int* counts     = (int*)alloc(ENUM * 4);
  int* offsets    = (int*)alloc(ENUM * 4);
  int* nT         = (int*)alloc(2 * 4);
  int* tileE1     = (int*)alloc(NT1CAP * 4);
  int* tileM1     = (int*)alloc(NT1CAP * 4);
  int* tileE2     = (int*)alloc(NT2CAP * 4);
  int* tileM2     = (int*)alloc(NT2CAP * 4);
  int* top2e      = (int*)alloc((size_t)NTOK * 2 * 4);
  float* top2v    = (float*)alloc((size_t)NTOK * 2 * 4);
  int* tokA       = (int*)alloc((size_t)NTOK * 2 * 4);
  float* assignW  = (float*)alloc((size_t)APAD * 4);
  int* histBase   = (int*)alloc((size_t)NBLK * 8 * 4);
  float* gatePart = (float*)alloc((size_t)NBLK * 8 * 4);
  u16* W1T        = (u16*)alloc((size_t)ENUM * FDIM * DDIM * 2);
  u16* W2T        = (u16*)alloc((size_t)ENUM * DDIM * FDIM * 2);
  u16* Xg         = (u16*)alloc((size_t)APAD * DDIM * 2);
  u16* hbuf       = (u16*)alloc((size_t)APAD * FDIM * 2);
  u16* z          = Xg;   // alias: Xg dead after gemm1
  (void)in_sizes; (void)n_in; (void)out_size; (void)ws_size;  // ~203 MB used

  (void)hipFuncSetAttribute((const void*)gemm1_kernel,
                            hipFuncAttributeMaxDynamicSharedMemorySize, 131072);
  (void)hipFuncSetAttribute((const void*)gemm2_kernel,
                            hipFuncAttributeMaxDynamicSharedMemorySize, 98304);

  transpose_kernel<<<dim3(256, 16), 256, 0, stream>>>(W1, W2, W1T, W2T);
  router_kernel<<<NBLK, 256, 0, stream>>>(x, Wr, br, top2e, top2v, histBase,
                                          gatePart);
  scan_kernel<<<1, 256, 0, stream>>>(histBase, gatePart, offsets, counts,
                                     tileE1, tileM1, tileE2, tileM2, nT,
                                     out + (size_t)NTOK * DDIM);
  place_kernel<<<NBLK, 256, 0, stream>>>(x, top2e, top2v, histBase, offsets,
                                         tokA, assignW, Xg);
  gemm1_kernel<<<G1GRID, 512, 131072, stream>>>(
      Xg, W1T, b1, hbuf, counts, offsets, tileE1, tileM1, nT);
  gemm2_kernel<<<G2GRID, 512, 98304, stream>>>(
      hbuf, W2T, b2, assignW, counts, offsets, tileE2, tileM2, nT, z);
  combine_kernel<<<NTOK / 4, 256, 0, stream>>>(z, tokA, out);
}